// Round 8
// baseline (200.997 us; speedup 1.0000x reference)
//
#include <hip/hip_runtime.h>

// MultiHeadAttention: out = softmax((XWq^T)(XWk^T)^T / 8) (XWv^T) Wo^T
// B=2, L=2048, DIM=1024, H=16, D=64. fp32 in/out, bf16 MFMA compute.
//
// R8: GEMMs get (1) XOR-swizzled LDS tiles (kills 8-way b128 read conflicts),
//     (2) double-buffered BK=32 with ONE barrier per k-iter (attn6 pattern),
//     (3) 8B vectorized epilogues: Q/K via operand-swapped MFMA (C^T -> 4
//     consecutive d/lane), V via non-swapped (4 consecutive seq/lane).
//     Global layouts byte-identical to R7; attn6 unchanged.

#define DIMN 1024
#define NH 16
#define HD 64
#define BB 2
#define LL 2048

typedef float f32x4 __attribute__((ext_vector_type(4)));
typedef short s16x8 __attribute__((ext_vector_type(8)));

#define QSCALE 0.18033688011112042f  // log2(e)/8, folds softmax exp2 domain

static __device__ __forceinline__ unsigned short f2bf(float f) {
  unsigned u = __float_as_uint(f);
  u += 0x7fffu + ((u >> 16) & 1u);   // RNE
  return (unsigned short)(u >> 16);
}
static __device__ __forceinline__ unsigned packbf2(float lo, float hi) {
  return (unsigned)f2bf(lo) | ((unsigned)f2bf(hi) << 16);
}
static __device__ __forceinline__ float xexp2(float x) {
#if __has_builtin(__builtin_amdgcn_exp2f)
  return __builtin_amdgcn_exp2f(x);
#else
  return exp2f(x);
#endif
}
static __device__ __forceinline__ s16x8 cvt8(float4 a, float4 b) {
  s16x8 r;
  r[0] = (short)f2bf(a.x); r[1] = (short)f2bf(a.y);
  r[2] = (short)f2bf(a.z); r[3] = (short)f2bf(a.w);
  r[4] = (short)f2bf(b.x); r[5] = (short)f2bf(b.y);
  r[6] = (short)f2bf(b.z); r[7] = (short)f2bf(b.w);
  return r;
}
// async global->LDS, 16B/lane; LDS dest is wave-uniform base + lane*16
static __device__ __forceinline__ void gld16(const unsigned short* g,
                                             unsigned short* l) {
#if __has_builtin(__builtin_amdgcn_global_load_lds)
  __builtin_amdgcn_global_load_lds(
      (const __attribute__((address_space(1))) void*)g,
      (__attribute__((address_space(3))) void*)l, 16, 0, 0);
#else
  ((uint4*)l)[threadIdx.x & 63] = ((const uint4*)g)[0];
#endif
}

// V storage permutation within each 128-seq group (bits of s):
// pos = b6*64 + b5*32 + (bits3:2)*8 + bit4*4 + bits1:0  — keeps low 2 bits.
static __device__ __forceinline__ int vpos(int s128) {
  return (s128 & 0x60) | ((s128 & 0x0C) << 1) | ((s128 & 0x10) >> 2) | (s128 & 3);
}

// ---------------- fp32 -> bf16 pre-convert (X + 4 weights) ----------------
__global__ __launch_bounds__(256) void cvt_all(
    const float* __restrict__ X, const float* __restrict__ Wq,
    const float* __restrict__ Wk, const float* __restrict__ Wv,
    const float* __restrict__ Wo, unsigned short* __restrict__ out) {
  const int blk = blockIdx.x;
  const float* src;
  unsigned short* dst;
  size_t off;
  if (blk < 2048) {
    src = X; dst = out; off = (size_t)blk * 2048;
  } else {
    int s = (blk - 2048) >> 9;
    src = (s == 0) ? Wq : (s == 1) ? Wk : (s == 2) ? Wv : Wo;
    dst = out + ((size_t)1 << 22) + (size_t)s * (1u << 20);
    off = (size_t)((blk - 2048) & 511) * 2048;
  }
  size_t i = off + (size_t)threadIdx.x * 8;
  float4 v0 = *(const float4*)(src + i);
  float4 v1 = *(const float4*)(src + i + 4);
  uint4 o;
  o.x = packbf2(v0.x, v0.y); o.y = packbf2(v0.z, v0.w);
  o.z = packbf2(v1.x, v1.y); o.w = packbf2(v1.z, v1.w);
  *(uint4*)(dst + i) = o;
}

// ---------------- fused QKV projection, 128x128, dbuf + swizzle ----------------
// grid (32, 24), block 256 (4 waves; wave owns a 64x64 quadrant).
__global__ __launch_bounds__(256) void gemm_qkv(
    const unsigned short* __restrict__ Xb, const unsigned short* __restrict__ Wb,
    unsigned short* __restrict__ Qb, unsigned short* __restrict__ Kb,
    unsigned short* __restrict__ VT) {
  __shared__ __align__(16) unsigned short Al[2][128 * 32];
  __shared__ __align__(16) unsigned short Bl[2][128 * 32];
  const int m0 = blockIdx.x * 128;
  const int n0g = blockIdx.y * 128;
  const int sel = n0g >> 10;
  const int tid = threadIdx.x;
  const int w = tid >> 6, lane = tid & 63;
  const int c = lane & 15, quad = lane >> 4;
  const int wm = (w & 1) * 64, wn = (w >> 1) * 64;

  f32x4 zero = {0.f, 0.f, 0.f, 0.f};
  f32x4 acc[4][4];
#pragma unroll
  for (int i = 0; i < 4; ++i)
#pragma unroll
    for (int j = 0; j < 4; ++j) acc[i][j] = zero;

  // staging: wave w owns rows [w*32, w*32+32); source col carries the swizzle
  const int srow = w * 32 + (lane >> 2);
  const int ksw = ((lane >> 2) ^ (lane >> 4)) & 3;
  const int scol = ((lane & 3) ^ ksw) * 8;
  const unsigned short* gA = Xb + (size_t)(m0 + srow) * DIMN + scol;
  const unsigned short* gB = Wb + (size_t)(n0g + srow) * DIMN + scol;

  // read-side swizzle key (row mod 16 == c in all fragment reads)
  const int kc = (c ^ (c >> 2)) & 3;
  const int rda = (quad ^ kc) * 8;

#define STAGEQ(buf, k0)                                      \
  do {                                                       \
    gld16(gA + (k0), &Al[buf][(w * 32) * 32]);               \
    gld16(gA + (k0) + 16 * DIMN, &Al[buf][(w * 32 + 16) * 32]); \
    gld16(gB + (k0), &Bl[buf][(w * 32) * 32]);               \
    gld16(gB + (k0) + 16 * DIMN, &Bl[buf][(w * 32 + 16) * 32]); \
  } while (0)

  STAGEQ(0, 0);
  for (int kt = 0; kt < DIMN / 32; ++kt) {
    __syncthreads();
    if (kt + 1 < DIMN / 32) STAGEQ((kt + 1) & 1, (kt + 1) * 32);
    const unsigned short* At = Al[kt & 1];
    const unsigned short* Bt = Bl[kt & 1];
    s16x8 a[4], b[4];
#pragma unroll
    for (int i = 0; i < 4; ++i)
      a[i] = *(const s16x8*)&At[(wm + i * 16 + c) * 32 + rda];
#pragma unroll
    for (int j = 0; j < 4; ++j)
      b[j] = *(const s16x8*)&Bt[(wn + j * 16 + c) * 32 + rda];
    if (sel != 2) {
#pragma unroll
      for (int i = 0; i < 4; ++i)
#pragma unroll
        for (int j = 0; j < 4; ++j)  // swapped -> C^T (4 consecutive d / lane)
          acc[i][j] = __builtin_amdgcn_mfma_f32_16x16x32_bf16(b[j], a[i], acc[i][j], 0, 0, 0);
    } else {
#pragma unroll
      for (int i = 0; i < 4; ++i)
#pragma unroll
        for (int j = 0; j < 4; ++j)  // normal (4 consecutive seq / lane)
          acc[i][j] = __builtin_amdgcn_mfma_f32_16x16x32_bf16(a[i], b[j], acc[i][j], 0, 0, 0);
    }
  }
#undef STAGEQ

  const int n0 = n0g & 1023;
  if (sel != 2) {
    // C^T: row = n (d), col = seq. 8B packed stores, layout [B,H,L,D].
    unsigned short* Out = (sel == 0) ? Qb : Kb;
    const float scale = (sel == 0) ? QSCALE : 1.0f;
    const int bi = (m0 + wm) >> 11;
#pragma unroll
    for (int i = 0; i < 4; ++i) {
      const int li = (m0 + wm + i * 16 + c) & 2047;
#pragma unroll
      for (int j = 0; j < 4; ++j) {
        const int nq = n0 + wn + j * 16 + quad * 4;
        const int h = nq >> 6, d = nq & 63;
        uint2 st;
        st.x = packbf2(acc[i][j][0] * scale, acc[i][j][1] * scale);
        st.y = packbf2(acc[i][j][2] * scale, acc[i][j][3] * scale);
        *(uint2*)&Out[(((size_t)bi * NH + h) * LL + li) * HD + d] = st;
      }
    }
  } else {
    // normal C: row = seq, col = n (d). 8B packed stores, layout [B,H,D,L]
    // with vpos permutation per 128-seq group (keeps low 2 bits -> contiguous).
    const int bi = m0 >> 11;
    const int mlo = m0 & 2047;
#pragma unroll
    for (int i = 0; i < 4; ++i) {
      const int pos = mlo + vpos(wm + i * 16 + quad * 4);
#pragma unroll
      for (int j = 0; j < 4; ++j) {
        const int nv = n0 + wn + j * 16 + c;
        const int h = nv >> 6, d = nv & 63;
        uint2 st;
        st.x = packbf2(acc[i][j][0], acc[i][j][1]);
        st.y = packbf2(acc[i][j][2], acc[i][j][3]);
        *(uint2*)&VT[(((size_t)bi * NH + h) * HD + d) * LL + pos] = st;
      }
    }
  }
}

// ---------------- output projection, 128x64, dbuf + swizzle ----------------
// grid (32, 16), block 256. Wave owns 64x32 quadrant.
__global__ __launch_bounds__(256) void gemm_o(
    const unsigned short* __restrict__ A, const unsigned short* __restrict__ Wob,
    float* __restrict__ Out) {
  __shared__ __align__(16) unsigned short Al[2][128 * 32];
  __shared__ __align__(16) unsigned short Bl[2][64 * 32];
  const int m0 = blockIdx.x * 128;
  const int n0 = blockIdx.y * 64;
  const int tid = threadIdx.x;
  const int w = tid >> 6, lane = tid & 63;
  const int c = lane & 15, quad = lane >> 4;
  const int wm = (w & 1) * 64, wn = (w >> 1) * 32;

  f32x4 zero = {0.f, 0.f, 0.f, 0.f};
  f32x4 acc[4][2];
#pragma unroll
  for (int i = 0; i < 4; ++i)
#pragma unroll
    for (int j = 0; j < 2; ++j) acc[i][j] = zero;

  const int srow = w * 32 + (lane >> 2);
  const int brow = w * 16 + (lane >> 2);
  const int ksw = ((lane >> 2) ^ (lane >> 4)) & 3;
  const int scol = ((lane & 3) ^ ksw) * 8;
  const unsigned short* gA = A + (size_t)(m0 + srow) * DIMN + scol;
  const unsigned short* gB = Wob + (size_t)(n0 + brow) * DIMN + scol;

  const int kc = (c ^ (c >> 2)) & 3;
  const int rda = (quad ^ kc) * 8;

#define STAGEO(buf, k0)                                      \
  do {                                                       \
    gld16(gA + (k0), &Al[buf][(w * 32) * 32]);               \
    gld16(gA + (k0) + 16 * DIMN, &Al[buf][(w * 32 + 16) * 32]); \
    gld16(gB + (k0), &Bl[buf][(w * 16) * 32]);               \
  } while (0)

  STAGEO(0, 0);
  for (int kt = 0; kt < DIMN / 32; ++kt) {
    __syncthreads();
    if (kt + 1 < DIMN / 32) STAGEO((kt + 1) & 1, (kt + 1) * 32);
    const unsigned short* At = Al[kt & 1];
    const unsigned short* Bt = Bl[kt & 1];
    s16x8 a[4], b[2];
#pragma unroll
    for (int i = 0; i < 4; ++i)
      a[i] = *(const s16x8*)&At[(wm + i * 16 + c) * 32 + rda];
#pragma unroll
    for (int j = 0; j < 2; ++j)
      b[j] = *(const s16x8*)&Bt[(wn + j * 16 + c) * 32 + rda];
#pragma unroll
    for (int i = 0; i < 4; ++i)
#pragma unroll
      for (int j = 0; j < 2; ++j)
        acc[i][j] = __builtin_amdgcn_mfma_f32_16x16x32_bf16(a[i], b[j], acc[i][j], 0, 0, 0);
  }
#undef STAGEO

#pragma unroll
  for (int i = 0; i < 4; ++i)
#pragma unroll
    for (int j = 0; j < 2; ++j)
#pragma unroll
      for (int r = 0; r < 4; ++r)
        Out[(size_t)(m0 + wm + i * 16 + quad * 4 + r) * DIMN + n0 + wn + j * 16 + c] =
            acc[i][j][r];
}

// ---------------- flash attention, 8 waves x 16 q-rows (unchanged R7) ----------------
__global__ __launch_bounds__(512) void attn6(
    const unsigned short* __restrict__ Qb, const unsigned short* __restrict__ Kb,
    const unsigned short* __restrict__ VT, unsigned short* __restrict__ AO) {
  __shared__ __align__(16) unsigned short Kl[2 * 128 * 64];   // 32 KB
  __shared__ __align__(16) unsigned short Vtl[2 * 64 * 128];  // 32 KB

  const int bh = blockIdx.y;
  const int tid = threadIdx.x;
  const int w = tid >> 6, lane = tid & 63;
  const int c = lane & 15, quad = lane >> 4;
  const int q0 = blockIdx.x * 128 + w * 16;

  const unsigned short* Qh = Qb + (size_t)bh * LL * HD;
  const unsigned short* Kh = Kb + (size_t)bh * LL * HD;
  const unsigned short* Vh = VT + (size_t)bh * HD * LL;   // [d][l], permuted

  s16x8 qf0 = *(const s16x8*)(Qh + (size_t)(q0 + c) * HD + quad * 8);
  s16x8 qf1 = *(const s16x8*)(Qh + (size_t)(q0 + c) * HD + 32 + quad * 8);

  f32x4 zero = {0.f, 0.f, 0.f, 0.f};
  f32x4 o[4];
  float lsum = 0.f;
#pragma unroll
  for (int dc = 0; dc < 4; ++dc) o[dc] = zero;

  const int l8 = lane >> 3, p8 = lane & 7;
  const unsigned short* gK = Kh + (size_t)(w * 16 + l8) * HD + ((p8 ^ l8) * 8);
  const int l16 = lane >> 4, p16 = lane & 15;
  const int vr0 = w * 8 + l16;
  const int vr1 = w * 8 + 4 + l16;
  const unsigned short* gV0 = Vh + (size_t)vr0 * LL + ((p16 ^ (vr0 & 15)) * 8);
  const unsigned short* gV1 = Vh + (size_t)vr1 * LL + ((p16 ^ (vr1 & 15)) * 8);

  const int kpa = (quad ^ (c & 7)) * 8;
  const int kpb = ((quad + 4) ^ (c & 7)) * 8;

#define STAGE(buf, k0)                                                        \
  do {                                                                        \
    unsigned short* lK_ = Kl + (buf) * (128 * 64) + (w * 16) * 64;            \
    unsigned short* lV_ = Vtl + (buf) * (64 * 128) + (w * 8) * 128;           \
    gld16(gK + (size_t)(k0) * HD, lK_);                                       \
    gld16(gK + (size_t)((k0) + 8) * HD, lK_ + 8 * 64);                        \
    gld16(gV0 + (k0), lV_);                                                   \
    gld16(gV1 + (k0), lV_ + 4 * 128);                                         \
  } while (0)

  STAGE(0, 0);

  for (int it = 0; it < LL / 128; ++it) {
    __syncthreads();
    if (it + 1 < LL / 128) STAGE((it + 1) & 1, (it + 1) * 128);
    const unsigned short* Kt = Kl + (it & 1) * (128 * 64);
    const unsigned short* Vt = Vtl + (it & 1) * (64 * 128);

#pragma unroll
    for (int g = 0; g < 2; ++g) {
      f32x4 s[4];
#pragma unroll
      for (int t4 = 0; t4 < 4; ++t4) {
        const unsigned short* kr = Kt + ((g * 4 + t4) * 16 + c) * 64;
        s16x8 kfa = *(const s16x8*)(kr + kpa);
        s16x8 kfb = *(const s16x8*)(kr + kpb);
        s[t4] = __builtin_amdgcn_mfma_f32_16x16x32_bf16(kfa, qf0, zero, 0, 0, 0);
        s[t4] = __builtin_amdgcn_mfma_f32_16x16x32_bf16(kfb, qf1, s[t4], 0, 0, 0);
      }
      float p[4][4];
      float acc_l = 0.f;
#pragma unroll
      for (int t4 = 0; t4 < 4; ++t4)
#pragma unroll
        for (int r = 0; r < 4; ++r) {
          float e = xexp2(s[t4][r]);
          p[t4][r] = e;
          acc_l += e;
        }
      lsum += acc_l;
#pragma unroll
      for (int kh = 0; kh < 2; ++kh) {
        const int kk = g * 2 + kh;
        unsigned pu[4];
        pu[0] = __builtin_amdgcn_perm(__float_as_uint(p[2 * kh][1]),
                                      __float_as_uint(p[2 * kh][0]), 0x07060302u);
        pu[1] = __builtin_amdgcn_perm(__float_as_uint(p[2 * kh][3]),
                                      __float_as_uint(p[2 * kh][2]), 0x07060302u);
        pu[2] = __builtin_amdgcn_perm(__float_as_uint(p[2 * kh + 1][1]),
                                      __float_as_uint(p[2 * kh + 1][0]), 0x07060302u);
        pu[3] = __builtin_amdgcn_perm(__float_as_uint(p[2 * kh + 1][3]),
                                      __float_as_uint(p[2 * kh + 1][2]), 0x07060302u);
        s16x8 pf = *(const s16x8*)pu;
#pragma unroll
        for (int dc = 0; dc < 4; ++dc) {
          s16x8 vf = *(const s16x8*)(Vt + (dc * 16 + c) * 128 + (((kk * 4 + quad) ^ c) * 8));
          o[dc] = __builtin_amdgcn_mfma_f32_16x16x32_bf16(vf, pf, o[dc], 0, 0, 0);
        }
      }
    }
  }
#undef STAGE

  const int bi = bh >> 4, h = bh & 15;
  float l = lsum;
  l += __shfl_xor(l, 16);
  l += __shfl_xor(l, 32);
  float inv = 1.0f / l;
  unsigned short* dst = AO + ((size_t)bi * LL + q0 + c) * DIMN + h * HD + quad * 4;
#pragma unroll
  for (int dc = 0; dc < 4; ++dc) {
    uint2 st;
    st.x = packbf2(o[dc][0] * inv, o[dc][1] * inv);
    st.y = packbf2(o[dc][2] * inv, o[dc][3] * inv);
    *(uint2*)(dst + dc * 16) = st;
  }
}

// ---------------- fp32 fallback path (1-wave GEMMs), ws < 48 MiB ----------------
__global__ __launch_bounds__(64) void qkv_proj_f(
    const float* __restrict__ X, const float* __restrict__ Wq,
    const float* __restrict__ Wk, const float* __restrict__ Wv,
    unsigned short* __restrict__ Qb, unsigned short* __restrict__ Kb,
    unsigned short* __restrict__ VT) {
  const int m0 = blockIdx.x * 64;
  const int n0g = blockIdx.y * 64;
  const int sel = n0g >> 10;
  const int n0 = n0g & 1023;
  const float* W = (sel == 0) ? Wq : (sel == 1) ? Wk : Wv;
  const int lane = threadIdx.x;
  const int c = lane & 15, quad = lane >> 4;

  f32x4 zero = {0.f, 0.f, 0.f, 0.f};
  f32x4 acc[4][4];
#pragma unroll
  for (int i = 0; i < 4; ++i)
#pragma unroll
    for (int j = 0; j < 4; ++j) acc[i][j] = zero;

  const float* ab = X + (size_t)(m0 + c) * DIMN + quad * 8;
  const float* bb = W + (size_t)(n0 + c) * DIMN + quad * 8;

  for (int k0 = 0; k0 < DIMN; k0 += 32) {
    s16x8 a[4], b[4];
#pragma unroll
    for (int i = 0; i < 4; ++i) {
      const float* pp = ab + i * 16 * DIMN + k0;
      a[i] = cvt8(*(const float4*)pp, *(const float4*)(pp + 4));
    }
#pragma unroll
    for (int j = 0; j < 4; ++j) {
      const float* pp = bb + j * 16 * DIMN + k0;
      b[j] = cvt8(*(const float4*)pp, *(const float4*)(pp + 4));
    }
    if (sel != 2) {
#pragma unroll
      for (int i = 0; i < 4; ++i)
#pragma unroll
        for (int j = 0; j < 4; ++j)
          acc[i][j] = __builtin_amdgcn_mfma_f32_16x16x32_bf16(a[i], b[j], acc[i][j], 0, 0, 0);
    } else {
#pragma unroll
      for (int i = 0; i < 4; ++i)
#pragma unroll
        for (int j = 0; j < 4; ++j)
          acc[i][j] = __builtin_amdgcn_mfma_f32_16x16x32_bf16(b[j], a[i], acc[i][j], 0, 0, 0);
    }
  }

  if (sel != 2) {
    unsigned short* Out = (sel == 0) ? Qb : Kb;
    const float scale = (sel == 0) ? QSCALE : 1.0f;
#pragma unroll
    for (int i = 0; i < 4; ++i)
#pragma unroll
      for (int j = 0; j < 4; ++j)
#pragma unroll
        for (int r = 0; r < 4; ++r) {
          int row = m0 + i * 16 + quad * 4 + r;
          int nl = n0 + j * 16 + c;
          int bi = row >> 11, li = row & 2047;
          int h = nl >> 6, d = nl & 63;
          Out[(((size_t)bi * NH + h) * LL + li) * HD + d] = f2bf(acc[i][j][r] * scale);
        }
  } else {
#pragma unroll
    for (int i = 0; i < 4; ++i) {
#pragma unroll
      for (int j = 0; j < 4; ++j)
#pragma unroll
        for (int r = 0; r < 4; ++r) {
          int n = n0 + j * 16 + quad * 4 + r;
          int s128 = (m0 & 64) + i * 16 + c;
          int m = (m0 & ~127) + vpos(s128);
          int h = n >> 6, d = n & 63;
          int bi = m0 >> 11;
          VT[(((size_t)bi * NH + h) * HD + d) * LL + (m & 2047)] = f2bf(acc[i][j][r]);
        }
    }
  }
}

__global__ __launch_bounds__(64) void o_proj_f(
    const unsigned short* __restrict__ A, const float* __restrict__ Wo,
    float* __restrict__ Out) {
  const int m0 = blockIdx.x * 64, n0 = blockIdx.y * 64;
  const int lane = threadIdx.x;
  const int c = lane & 15, quad = lane >> 4;

  f32x4 zero = {0.f, 0.f, 0.f, 0.f};
  f32x4 acc[4][4];
#pragma unroll
  for (int i = 0; i < 4; ++i)
#pragma unroll
    for (int j = 0; j < 4; ++j) acc[i][j] = zero;

  const unsigned short* ab = A + (size_t)(m0 + c) * DIMN + quad * 8;
  const float* bb = Wo + (size_t)(n0 + c) * DIMN + quad * 8;

  for (int k0 = 0; k0 < DIMN; k0 += 32) {
    s16x8 a[4], b[4];
#pragma unroll
    for (int i = 0; i < 4; ++i) a[i] = *(const s16x8*)(ab + i * 16 * DIMN + k0);
#pragma unroll
    for (int j = 0; j < 4; ++j) {
      const float* pp = bb + j * 16 * DIMN + k0;
      b[j] = cvt8(*(const float4*)pp, *(const float4*)(pp + 4));
    }
#pragma unroll
    for (int i = 0; i < 4; ++i)
#pragma unroll
      for (int j = 0; j < 4; ++j)
        acc[i][j] = __builtin_amdgcn_mfma_f32_16x16x32_bf16(a[i], b[j], acc[i][j], 0, 0, 0);
  }

#pragma unroll
  for (int i = 0; i < 4; ++i)
#pragma unroll
    for (int j = 0; j < 4; ++j)
#pragma unroll
      for (int r = 0; r < 4; ++r)
        Out[(size_t)(m0 + i * 16 + quad * 4 + r) * DIMN + n0 + j * 16 + c] = acc[i][j][r];
}

extern "C" void kernel_launch(void* const* d_in, const int* in_sizes, int n_in,
                              void* d_out, int out_size, void* d_ws, size_t ws_size,
                              hipStream_t stream) {
  const float* X = (const float*)d_in[0];
  const float* Wq = (const float*)d_in[1];
  const float* Wk = (const float*)d_in[2];
  const float* Wv = (const float*)d_in[3];
  const float* Wo = (const float*)d_in[4];
  float* Out = (float*)d_out;

  const size_t M1 = (size_t)1 << 20;
  unsigned short* ws16 = (unsigned short*)d_ws;

  if (ws_size >= (size_t)48 * 1024 * 1024) {
    unsigned short* Xb = ws16;            // 4M elems
    unsigned short* Wb = ws16 + 4 * M1;   // 4 x 1M (Wq,Wk,Wv,Wo contiguous)
    unsigned short* Qb = ws16 + 8 * M1;
    unsigned short* Kb = ws16 + 12 * M1;
    unsigned short* VT = ws16 + 16 * M1;
    unsigned short* AO = ws16 + 20 * M1;
    cvt_all<<<4096, 256, 0, stream>>>(X, Wq, Wk, Wv, Wo, ws16);
    gemm_qkv<<<dim3(32, 24), 256, 0, stream>>>(Xb, Wb, Qb, Kb, VT);
    attn6<<<dim3(LL / 128, BB * NH), 512, 0, stream>>>(Qb, Kb, VT, AO);
    gemm_o<<<dim3(32, 16), 256, 0, stream>>>(AO, Wb + 3 * M1, Out);
  } else {
    unsigned short* Qb = ws16;
    unsigned short* Kb = ws16 + 4 * M1;
    unsigned short* VT = ws16 + 8 * M1;
    unsigned short* AO = ws16 + 12 * M1;
    qkv_proj_f<<<dim3(64, 48), 64, 0, stream>>>(X, Wq, Wk, Wv, Qb, Kb, VT);
    attn6<<<dim3(LL / 128, BB * NH), 512, 0, stream>>>(Qb, Kb, VT, AO);
    o_proj_f<<<dim3(64, 16), 64, 0, stream>>>(AO, Wo, Out);
  }
}

// Round 9
// 188.257 us; speedup vs baseline: 1.0677x; 1.0677x over previous
//
#include <hip/hip_runtime.h>

// MultiHeadAttention: out = softmax((XWq^T)(XWk^T)^T / 8) (XWv^T) Wo^T
// B=2, L=2048, DIM=1024, H=16, D=64. fp32 in/out, bf16 MFMA compute.
//
// R9: revert R8's dbuf+swizzle K-loop (regressed: conflicts unchanged 3.1M,
//     VALU up 11->27%) back to R7's measured 2-barrier single-buffer loop;
//     KEEP R8's validated vectorized epilogues (Q/K operand-swapped -> C^T ->
//     uint2 stores; V normal + vpos -> uint2 stores). attn6 unchanged.

#define DIMN 1024
#define NH 16
#define HD 64
#define BB 2
#define LL 2048

typedef float f32x4 __attribute__((ext_vector_type(4)));
typedef short s16x8 __attribute__((ext_vector_type(8)));

#define QSCALE 0.18033688011112042f  // log2(e)/8, folds softmax exp2 domain

static __device__ __forceinline__ unsigned short f2bf(float f) {
  unsigned u = __float_as_uint(f);
  u += 0x7fffu + ((u >> 16) & 1u);   // RNE
  return (unsigned short)(u >> 16);
}
static __device__ __forceinline__ unsigned packbf2(float lo, float hi) {
  return (unsigned)f2bf(lo) | ((unsigned)f2bf(hi) << 16);
}
static __device__ __forceinline__ float xexp2(float x) {
#if __has_builtin(__builtin_amdgcn_exp2f)
  return __builtin_amdgcn_exp2f(x);
#else
  return exp2f(x);
#endif
}
static __device__ __forceinline__ s16x8 cvt8(float4 a, float4 b) {
  s16x8 r;
  r[0] = (short)f2bf(a.x); r[1] = (short)f2bf(a.y);
  r[2] = (short)f2bf(a.z); r[3] = (short)f2bf(a.w);
  r[4] = (short)f2bf(b.x); r[5] = (short)f2bf(b.y);
  r[6] = (short)f2bf(b.z); r[7] = (short)f2bf(b.w);
  return r;
}
// async global->LDS, 16B/lane; LDS dest is wave-uniform base + lane*16
static __device__ __forceinline__ void gld16(const unsigned short* g,
                                             unsigned short* l) {
#if __has_builtin(__builtin_amdgcn_global_load_lds)
  __builtin_amdgcn_global_load_lds(
      (const __attribute__((address_space(1))) void*)g,
      (__attribute__((address_space(3))) void*)l, 16, 0, 0);
#else
  ((uint4*)l)[threadIdx.x & 63] = ((const uint4*)g)[0];
#endif
}

// V storage permutation within each 128-seq group (bits of s):
// pos = b6*64 + b5*32 + (bits3:2)*8 + bit4*4 + bits1:0  — keeps low 2 bits.
static __device__ __forceinline__ int vpos(int s128) {
  return (s128 & 0x60) | ((s128 & 0x0C) << 1) | ((s128 & 0x10) >> 2) | (s128 & 3);
}

// ---------------- fp32 -> bf16 pre-convert (X + 4 weights) ----------------
__global__ __launch_bounds__(256) void cvt_all(
    const float* __restrict__ X, const float* __restrict__ Wq,
    const float* __restrict__ Wk, const float* __restrict__ Wv,
    const float* __restrict__ Wo, unsigned short* __restrict__ out) {
  const int blk = blockIdx.x;
  const float* src;
  unsigned short* dst;
  size_t off;
  if (blk < 2048) {
    src = X; dst = out; off = (size_t)blk * 2048;
  } else {
    int s = (blk - 2048) >> 9;
    src = (s == 0) ? Wq : (s == 1) ? Wk : (s == 2) ? Wv : Wo;
    dst = out + ((size_t)1 << 22) + (size_t)s * (1u << 20);
    off = (size_t)((blk - 2048) & 511) * 2048;
  }
  size_t i = off + (size_t)threadIdx.x * 8;
  float4 v0 = *(const float4*)(src + i);
  float4 v1 = *(const float4*)(src + i + 4);
  uint4 o;
  o.x = packbf2(v0.x, v0.y); o.y = packbf2(v0.z, v0.w);
  o.z = packbf2(v1.x, v1.y); o.w = packbf2(v1.z, v1.w);
  *(uint4*)(dst + i) = o;
}

// ---------------- fused QKV projection, 128x128 (R7 loop + R8 epilogue) ----------------
// grid (32, 24), block 256 (4 waves; wave owns a 64x64 quadrant).
__global__ __launch_bounds__(256) void gemm_qkv(
    const unsigned short* __restrict__ Xb, const unsigned short* __restrict__ Wb,
    unsigned short* __restrict__ Qb, unsigned short* __restrict__ Kb,
    unsigned short* __restrict__ VT) {
  __shared__ __align__(16) unsigned short Al[128 * 32];
  __shared__ __align__(16) unsigned short Bl[128 * 32];
  const int m0 = blockIdx.x * 128;
  const int n0g = blockIdx.y * 128;
  const int sel = n0g >> 10;
  const int tid = threadIdx.x;
  const int w = tid >> 6, lane = tid & 63;
  const int c = lane & 15, quad = lane >> 4;
  const int wm = (w & 1) * 64, wn = (w >> 1) * 64;

  f32x4 zero = {0.f, 0.f, 0.f, 0.f};
  f32x4 acc[4][4];
#pragma unroll
  for (int i = 0; i < 4; ++i)
#pragma unroll
    for (int j = 0; j < 4; ++j) acc[i][j] = zero;

  const int srow = w * 32 + (lane >> 2);
  const int scol = (lane & 3) * 8;
  const unsigned short* gA = Xb + (size_t)(m0 + srow) * DIMN + scol;
  const unsigned short* gB = Wb + (size_t)(n0g + srow) * DIMN + scol;
  unsigned short* lA0 = Al + (w * 32) * 32;
  unsigned short* lA1 = Al + (w * 32 + 16) * 32;
  unsigned short* lB0 = Bl + (w * 32) * 32;
  unsigned short* lB1 = Bl + (w * 32 + 16) * 32;

  for (int k0 = 0; k0 < DIMN; k0 += 32) {
    __syncthreads();
    gld16(gA + k0, lA0);
    gld16(gA + k0 + 16 * DIMN, lA1);
    gld16(gB + k0, lB0);
    gld16(gB + k0 + 16 * DIMN, lB1);
    __syncthreads();
    s16x8 a[4], b[4];
#pragma unroll
    for (int i = 0; i < 4; ++i)
      a[i] = *(const s16x8*)&Al[(wm + i * 16 + c) * 32 + quad * 8];
#pragma unroll
    for (int j = 0; j < 4; ++j)
      b[j] = *(const s16x8*)&Bl[(wn + j * 16 + c) * 32 + quad * 8];
    if (sel != 2) {
#pragma unroll
      for (int i = 0; i < 4; ++i)
#pragma unroll
        for (int j = 0; j < 4; ++j)  // swapped -> C^T (4 consecutive d / lane)
          acc[i][j] = __builtin_amdgcn_mfma_f32_16x16x32_bf16(b[j], a[i], acc[i][j], 0, 0, 0);
    } else {
#pragma unroll
      for (int i = 0; i < 4; ++i)
#pragma unroll
        for (int j = 0; j < 4; ++j)  // normal (4 consecutive seq / lane)
          acc[i][j] = __builtin_amdgcn_mfma_f32_16x16x32_bf16(a[i], b[j], acc[i][j], 0, 0, 0);
    }
  }

  const int n0 = n0g & 1023;
  if (sel != 2) {
    // C^T: row = n (d), col = seq. 8B packed stores, layout [B,H,L,D].
    unsigned short* Out = (sel == 0) ? Qb : Kb;
    const float scale = (sel == 0) ? QSCALE : 1.0f;
    const int bi = (m0 + wm) >> 11;
#pragma unroll
    for (int i = 0; i < 4; ++i) {
      const int li = (m0 + wm + i * 16 + c) & 2047;
#pragma unroll
      for (int j = 0; j < 4; ++j) {
        const int nq = n0 + wn + j * 16 + quad * 4;
        const int h = nq >> 6, d = nq & 63;
        uint2 st;
        st.x = packbf2(acc[i][j][0] * scale, acc[i][j][1] * scale);
        st.y = packbf2(acc[i][j][2] * scale, acc[i][j][3] * scale);
        *(uint2*)&Out[(((size_t)bi * NH + h) * LL + li) * HD + d] = st;
      }
    }
  } else {
    // normal C: row = seq, col = n (d). 8B packed stores, layout [B,H,D,L]
    // with vpos permutation per 128-seq group (keeps low 2 bits -> contiguous).
    const int bi = m0 >> 11;
    const int mlo = m0 & 2047;
#pragma unroll
    for (int i = 0; i < 4; ++i) {
      const int pos = mlo + vpos(wm + i * 16 + quad * 4);
#pragma unroll
      for (int j = 0; j < 4; ++j) {
        const int nv = n0 + wn + j * 16 + c;
        const int h = nv >> 6, d = nv & 63;
        uint2 st;
        st.x = packbf2(acc[i][j][0], acc[i][j][1]);
        st.y = packbf2(acc[i][j][2], acc[i][j][3]);
        *(uint2*)&VT[(((size_t)bi * NH + h) * HD + d) * LL + pos] = st;
      }
    }
  }
}

// ---------------- output projection, 128x64 (R7 loop) ----------------
// grid (32, 16), block 256. Wave owns 64x32 quadrant.
__global__ __launch_bounds__(256) void gemm_o(
    const unsigned short* __restrict__ A, const unsigned short* __restrict__ Wob,
    float* __restrict__ Out) {
  __shared__ __align__(16) unsigned short Al[128 * 32];
  __shared__ __align__(16) unsigned short Bl[64 * 32];
  const int m0 = blockIdx.x * 128;
  const int n0 = blockIdx.y * 64;
  const int tid = threadIdx.x;
  const int w = tid >> 6, lane = tid & 63;
  const int c = lane & 15, quad = lane >> 4;
  const int wm = (w & 1) * 64, wn = (w >> 1) * 32;

  f32x4 zero = {0.f, 0.f, 0.f, 0.f};
  f32x4 acc[4][2];
#pragma unroll
  for (int i = 0; i < 4; ++i)
#pragma unroll
    for (int j = 0; j < 2; ++j) acc[i][j] = zero;

  const int srow = w * 32 + (lane >> 2);
  const int brow = w * 16 + (lane >> 2);
  const int scol = (lane & 3) * 8;
  const unsigned short* gA = A + (size_t)(m0 + srow) * DIMN + scol;
  const unsigned short* gB = Wob + (size_t)(n0 + brow) * DIMN + scol;
  unsigned short* lA0 = Al + (w * 32) * 32;
  unsigned short* lA1 = Al + (w * 32 + 16) * 32;
  unsigned short* lB0 = Bl + (w * 16) * 32;

  for (int k0 = 0; k0 < DIMN; k0 += 32) {
    __syncthreads();
    gld16(gA + k0, lA0);
    gld16(gA + k0 + 16 * DIMN, lA1);
    gld16(gB + k0, lB0);
    __syncthreads();
    s16x8 a[4], b[2];
#pragma unroll
    for (int i = 0; i < 4; ++i)
      a[i] = *(const s16x8*)&Al[(wm + i * 16 + c) * 32 + quad * 8];
#pragma unroll
    for (int j = 0; j < 2; ++j)
      b[j] = *(const s16x8*)&Bl[(wn + j * 16 + c) * 32 + quad * 8];
#pragma unroll
    for (int i = 0; i < 4; ++i)
#pragma unroll
      for (int j = 0; j < 2; ++j)
        acc[i][j] = __builtin_amdgcn_mfma_f32_16x16x32_bf16(a[i], b[j], acc[i][j], 0, 0, 0);
  }

#pragma unroll
  for (int i = 0; i < 4; ++i)
#pragma unroll
    for (int j = 0; j < 2; ++j)
#pragma unroll
      for (int r = 0; r < 4; ++r)
        Out[(size_t)(m0 + wm + i * 16 + quad * 4 + r) * DIMN + n0 + wn + j * 16 + c] =
            acc[i][j][r];
}

// ---------------- flash attention, 8 waves x 16 q-rows (unchanged R7) ----------------
__global__ __launch_bounds__(512) void attn6(
    const unsigned short* __restrict__ Qb, const unsigned short* __restrict__ Kb,
    const unsigned short* __restrict__ VT, unsigned short* __restrict__ AO) {
  __shared__ __align__(16) unsigned short Kl[2 * 128 * 64];   // 32 KB
  __shared__ __align__(16) unsigned short Vtl[2 * 64 * 128];  // 32 KB

  const int bh = blockIdx.y;
  const int tid = threadIdx.x;
  const int w = tid >> 6, lane = tid & 63;
  const int c = lane & 15, quad = lane >> 4;
  const int q0 = blockIdx.x * 128 + w * 16;

  const unsigned short* Qh = Qb + (size_t)bh * LL * HD;
  const unsigned short* Kh = Kb + (size_t)bh * LL * HD;
  const unsigned short* Vh = VT + (size_t)bh * HD * LL;   // [d][l], permuted

  s16x8 qf0 = *(const s16x8*)(Qh + (size_t)(q0 + c) * HD + quad * 8);
  s16x8 qf1 = *(const s16x8*)(Qh + (size_t)(q0 + c) * HD + 32 + quad * 8);

  f32x4 zero = {0.f, 0.f, 0.f, 0.f};
  f32x4 o[4];
  float lsum = 0.f;
#pragma unroll
  for (int dc = 0; dc < 4; ++dc) o[dc] = zero;

  const int l8 = lane >> 3, p8 = lane & 7;
  const unsigned short* gK = Kh + (size_t)(w * 16 + l8) * HD + ((p8 ^ l8) * 8);
  const int l16 = lane >> 4, p16 = lane & 15;
  const int vr0 = w * 8 + l16;
  const int vr1 = w * 8 + 4 + l16;
  const unsigned short* gV0 = Vh + (size_t)vr0 * LL + ((p16 ^ (vr0 & 15)) * 8);
  const unsigned short* gV1 = Vh + (size_t)vr1 * LL + ((p16 ^ (vr1 & 15)) * 8);

  const int kpa = (quad ^ (c & 7)) * 8;
  const int kpb = ((quad + 4) ^ (c & 7)) * 8;

#define STAGE(buf, k0)                                                        \
  do {                                                                        \
    unsigned short* lK_ = Kl + (buf) * (128 * 64) + (w * 16) * 64;            \
    unsigned short* lV_ = Vtl + (buf) * (64 * 128) + (w * 8) * 128;           \
    gld16(gK + (size_t)(k0) * HD, lK_);                                       \
    gld16(gK + (size_t)((k0) + 8) * HD, lK_ + 8 * 64);                        \
    gld16(gV0 + (k0), lV_);                                                   \
    gld16(gV1 + (k0), lV_ + 4 * 128);                                         \
  } while (0)

  STAGE(0, 0);

  for (int it = 0; it < LL / 128; ++it) {
    __syncthreads();
    if (it + 1 < LL / 128) STAGE((it + 1) & 1, (it + 1) * 128);
    const unsigned short* Kt = Kl + (it & 1) * (128 * 64);
    const unsigned short* Vt = Vtl + (it & 1) * (64 * 128);

#pragma unroll
    for (int g = 0; g < 2; ++g) {
      f32x4 s[4];
#pragma unroll
      for (int t4 = 0; t4 < 4; ++t4) {
        const unsigned short* kr = Kt + ((g * 4 + t4) * 16 + c) * 64;
        s16x8 kfa = *(const s16x8*)(kr + kpa);
        s16x8 kfb = *(const s16x8*)(kr + kpb);
        s[t4] = __builtin_amdgcn_mfma_f32_16x16x32_bf16(kfa, qf0, zero, 0, 0, 0);
        s[t4] = __builtin_amdgcn_mfma_f32_16x16x32_bf16(kfb, qf1, s[t4], 0, 0, 0);
      }
      float p[4][4];
      float acc_l = 0.f;
#pragma unroll
      for (int t4 = 0; t4 < 4; ++t4)
#pragma unroll
        for (int r = 0; r < 4; ++r) {
          float e = xexp2(s[t4][r]);
          p[t4][r] = e;
          acc_l += e;
        }
      lsum += acc_l;
#pragma unroll
      for (int kh = 0; kh < 2; ++kh) {
        const int kk = g * 2 + kh;
        unsigned pu[4];
        pu[0] = __builtin_amdgcn_perm(__float_as_uint(p[2 * kh][1]),
                                      __float_as_uint(p[2 * kh][0]), 0x07060302u);
        pu[1] = __builtin_amdgcn_perm(__float_as_uint(p[2 * kh][3]),
                                      __float_as_uint(p[2 * kh][2]), 0x07060302u);
        pu[2] = __builtin_amdgcn_perm(__float_as_uint(p[2 * kh + 1][1]),
                                      __float_as_uint(p[2 * kh + 1][0]), 0x07060302u);
        pu[3] = __builtin_amdgcn_perm(__float_as_uint(p[2 * kh + 1][3]),
                                      __float_as_uint(p[2 * kh + 1][2]), 0x07060302u);
        s16x8 pf = *(const s16x8*)pu;
#pragma unroll
        for (int dc = 0; dc < 4; ++dc) {
          s16x8 vf = *(const s16x8*)(Vt + (dc * 16 + c) * 128 + (((kk * 4 + quad) ^ c) * 8));
          o[dc] = __builtin_amdgcn_mfma_f32_16x16x32_bf16(vf, pf, o[dc], 0, 0, 0);
        }
      }
    }
  }
#undef STAGE

  const int bi = bh >> 4, h = bh & 15;
  float l = lsum;
  l += __shfl_xor(l, 16);
  l += __shfl_xor(l, 32);
  float inv = 1.0f / l;
  unsigned short* dst = AO + ((size_t)bi * LL + q0 + c) * DIMN + h * HD + quad * 4;
#pragma unroll
  for (int dc = 0; dc < 4; ++dc) {
    uint2 st;
    st.x = packbf2(o[dc][0] * inv, o[dc][1] * inv);
    st.y = packbf2(o[dc][2] * inv, o[dc][3] * inv);
    *(uint2*)(dst + dc * 16) = st;
  }
}

// ---------------- fp32 fallback path (1-wave GEMMs), ws < 48 MiB ----------------
__global__ __launch_bounds__(64) void qkv_proj_f(
    const float* __restrict__ X, const float* __restrict__ Wq,
    const float* __restrict__ Wk, const float* __restrict__ Wv,
    unsigned short* __restrict__ Qb, unsigned short* __restrict__ Kb,
    unsigned short* __restrict__ VT) {
  const int m0 = blockIdx.x * 64;
  const int n0g = blockIdx.y * 64;
  const int sel = n0g >> 10;
  const int n0 = n0g & 1023;
  const float* W = (sel == 0) ? Wq : (sel == 1) ? Wk : Wv;
  const int lane = threadIdx.x;
  const int c = lane & 15, quad = lane >> 4;

  f32x4 zero = {0.f, 0.f, 0.f, 0.f};
  f32x4 acc[4][4];
#pragma unroll
  for (int i = 0; i < 4; ++i)
#pragma unroll
    for (int j = 0; j < 4; ++j) acc[i][j] = zero;

  const float* ab = X + (size_t)(m0 + c) * DIMN + quad * 8;
  const float* bb = W + (size_t)(n0 + c) * DIMN + quad * 8;

  for (int k0 = 0; k0 < DIMN; k0 += 32) {
    s16x8 a[4], b[4];
#pragma unroll
    for (int i = 0; i < 4; ++i) {
      const float* pp = ab + i * 16 * DIMN + k0;
      a[i] = cvt8(*(const float4*)pp, *(const float4*)(pp + 4));
    }
#pragma unroll
    for (int j = 0; j < 4; ++j) {
      const float* pp = bb + j * 16 * DIMN + k0;
      b[j] = cvt8(*(const float4*)pp, *(const float4*)(pp + 4));
    }
    if (sel != 2) {
#pragma unroll
      for (int i = 0; i < 4; ++i)
#pragma unroll
        for (int j = 0; j < 4; ++j)
          acc[i][j] = __builtin_amdgcn_mfma_f32_16x16x32_bf16(a[i], b[j], acc[i][j], 0, 0, 0);
    } else {
#pragma unroll
      for (int i = 0; i < 4; ++i)
#pragma unroll
        for (int j = 0; j < 4; ++j)
          acc[i][j] = __builtin_amdgcn_mfma_f32_16x16x32_bf16(b[j], a[i], acc[i][j], 0, 0, 0);
    }
  }

  if (sel != 2) {
    unsigned short* Out = (sel == 0) ? Qb : Kb;
    const float scale = (sel == 0) ? QSCALE : 1.0f;
#pragma unroll
    for (int i = 0; i < 4; ++i)
#pragma unroll
      for (int j = 0; j < 4; ++j)
#pragma unroll
        for (int r = 0; r < 4; ++r) {
          int row = m0 + i * 16 + quad * 4 + r;
          int nl = n0 + j * 16 + c;
          int bi = row >> 11, li = row & 2047;
          int h = nl >> 6, d = nl & 63;
          Out[(((size_t)bi * NH + h) * LL + li) * HD + d] = f2bf(acc[i][j][r] * scale);
        }
  } else {
#pragma unroll
    for (int i = 0; i < 4; ++i) {
#pragma unroll
      for (int j = 0; j < 4; ++j)
#pragma unroll
        for (int r = 0; r < 4; ++r) {
          int n = n0 + j * 16 + quad * 4 + r;
          int s128 = (m0 & 64) + i * 16 + c;
          int m = (m0 & ~127) + vpos(s128);
          int h = n >> 6, d = n & 63;
          int bi = m0 >> 11;
          VT[(((size_t)bi * NH + h) * HD + d) * LL + (m & 2047)] = f2bf(acc[i][j][r]);
        }
    }
  }
}

__global__ __launch_bounds__(64) void o_proj_f(
    const unsigned short* __restrict__ A, const float* __restrict__ Wo,
    float* __restrict__ Out) {
  const int m0 = blockIdx.x * 64, n0 = blockIdx.y * 64;
  const int lane = threadIdx.x;
  const int c = lane & 15, quad = lane >> 4;

  f32x4 zero = {0.f, 0.f, 0.f, 0.f};
  f32x4 acc[4][4];
#pragma unroll
  for (int i = 0; i < 4; ++i)
#pragma unroll
    for (int j = 0; j < 4; ++j) acc[i][j] = zero;

  const unsigned short* ab = A + (size_t)(m0 + c) * DIMN + quad * 8;
  const float* bb = Wo + (size_t)(n0 + c) * DIMN + quad * 8;

  for (int k0 = 0; k0 < DIMN; k0 += 32) {
    s16x8 a[4], b[4];
#pragma unroll
    for (int i = 0; i < 4; ++i) a[i] = *(const s16x8*)(ab + i * 16 * DIMN + k0);
#pragma unroll
    for (int j = 0; j < 4; ++j) {
      const float* pp = bb + j * 16 * DIMN + k0;
      b[j] = cvt8(*(const float4*)pp, *(const float4*)(pp + 4));
    }
#pragma unroll
    for (int i = 0; i < 4; ++i)
#pragma unroll
      for (int j = 0; j < 4; ++j)
        acc[i][j] = __builtin_amdgcn_mfma_f32_16x16x32_bf16(a[i], b[j], acc[i][j], 0, 0, 0);
  }

#pragma unroll
  for (int i = 0; i < 4; ++i)
#pragma unroll
    for (int j = 0; j < 4; ++j)
#pragma unroll
      for (int r = 0; r < 4; ++r)
        Out[(size_t)(m0 + i * 16 + quad * 4 + r) * DIMN + n0 + j * 16 + c] = acc[i][j][r];
}

extern "C" void kernel_launch(void* const* d_in, const int* in_sizes, int n_in,
                              void* d_out, int out_size, void* d_ws, size_t ws_size,
                              hipStream_t stream) {
  const float* X = (const float*)d_in[0];
  const float* Wq = (const float*)d_in[1];
  const float* Wk = (const float*)d_in[2];
  const float* Wv = (const float*)d_in[3];
  const float* Wo = (const float*)d_in[4];
  float* Out = (float*)d_out;

  const size_t M1 = (size_t)1 << 20;
  unsigned short* ws16 = (unsigned short*)d_ws;

  if (ws_size >= (size_t)48 * 1024 * 1024) {
    unsigned short* Xb = ws16;            // 4M elems
    unsigned short* Wb = ws16 + 4 * M1;   // 4 x 1M (Wq,Wk,Wv,Wo contiguous)
    unsigned short* Qb = ws16 + 8 * M1;
    unsigned short* Kb = ws16 + 12 * M1;
    unsigned short* VT = ws16 + 16 * M1;
    unsigned short* AO = ws16 + 20 * M1;
    cvt_all<<<4096, 256, 0, stream>>>(X, Wq, Wk, Wv, Wo, ws16);
    gemm_qkv<<<dim3(32, 24), 256, 0, stream>>>(Xb, Wb, Qb, Kb, VT);
    attn6<<<dim3(LL / 128, BB * NH), 512, 0, stream>>>(Qb, Kb, VT, AO);
    gemm_o<<<dim3(32, 16), 256, 0, stream>>>(AO, Wb + 3 * M1, Out);
  } else {
    unsigned short* Qb = ws16;
    unsigned short* Kb = ws16 + 4 * M1;
    unsigned short* VT = ws16 + 8 * M1;
    unsigned short* AO = ws16 + 12 * M1;
    qkv_proj_f<<<dim3(64, 48), 64, 0, stream>>>(X, Wq, Wk, Wv, Qb, Kb, VT);
    attn6<<<dim3(LL / 128, BB * NH), 512, 0, stream>>>(Qb, Kb, VT, AO);
    o_proj_f<<<dim3(64, 16), 64, 0, stream>>>(AO, Wo, Out);
  }
}

// Round 10
// 185.810 us; speedup vs baseline: 1.0817x; 1.0132x over previous
//
#include <hip/hip_runtime.h>

// MultiHeadAttention: out = softmax((XWq^T)(XWk^T)^T / 8) (XWv^T) Wo^T
// B=2, L=2048, DIM=1024, H=16, D=64. fp32 in/out, bf16 MFMA compute.
//
// R10: XCD-aware block swizzle (xcd = blockIdx % 8 heuristic) so co-resident
//      blocks per XCD share an L2-resident tile working set:
//      gemm_qkv 8m x 12n region/XCD (2MB X + 3MB W), attn6 4 bh x 16 q
//      (2MB K/V), gemm_o 4m x 16n (1MB A + 2MB Wo). Pure scheduling change;
//      kernels' arithmetic/layouts identical to R9.

#define DIMN 1024
#define NH 16
#define HD 64
#define BB 2
#define LL 2048

typedef float f32x4 __attribute__((ext_vector_type(4)));
typedef short s16x8 __attribute__((ext_vector_type(8)));

#define QSCALE 0.18033688011112042f  // log2(e)/8, folds softmax exp2 domain

static __device__ __forceinline__ unsigned short f2bf(float f) {
  unsigned u = __float_as_uint(f);
  u += 0x7fffu + ((u >> 16) & 1u);   // RNE
  return (unsigned short)(u >> 16);
}
static __device__ __forceinline__ unsigned packbf2(float lo, float hi) {
  return (unsigned)f2bf(lo) | ((unsigned)f2bf(hi) << 16);
}
static __device__ __forceinline__ float xexp2(float x) {
#if __has_builtin(__builtin_amdgcn_exp2f)
  return __builtin_amdgcn_exp2f(x);
#else
  return exp2f(x);
#endif
}
static __device__ __forceinline__ s16x8 cvt8(float4 a, float4 b) {
  s16x8 r;
  r[0] = (short)f2bf(a.x); r[1] = (short)f2bf(a.y);
  r[2] = (short)f2bf(a.z); r[3] = (short)f2bf(a.w);
  r[4] = (short)f2bf(b.x); r[5] = (short)f2bf(b.y);
  r[6] = (short)f2bf(b.z); r[7] = (short)f2bf(b.w);
  return r;
}
// async global->LDS, 16B/lane; LDS dest is wave-uniform base + lane*16
static __device__ __forceinline__ void gld16(const unsigned short* g,
                                             unsigned short* l) {
#if __has_builtin(__builtin_amdgcn_global_load_lds)
  __builtin_amdgcn_global_load_lds(
      (const __attribute__((address_space(1))) void*)g,
      (__attribute__((address_space(3))) void*)l, 16, 0, 0);
#else
  ((uint4*)l)[threadIdx.x & 63] = ((const uint4*)g)[0];
#endif
}

// V storage permutation within each 128-seq group (bits of s):
// pos = b6*64 + b5*32 + (bits3:2)*8 + bit4*4 + bits1:0  — keeps low 2 bits.
static __device__ __forceinline__ int vpos(int s128) {
  return (s128 & 0x60) | ((s128 & 0x0C) << 1) | ((s128 & 0x10) >> 2) | (s128 & 3);
}

// ---------------- fp32 -> bf16 pre-convert (X + 4 weights) ----------------
__global__ __launch_bounds__(256) void cvt_all(
    const float* __restrict__ X, const float* __restrict__ Wq,
    const float* __restrict__ Wk, const float* __restrict__ Wv,
    const float* __restrict__ Wo, unsigned short* __restrict__ out) {
  const int blk = blockIdx.x;
  const float* src;
  unsigned short* dst;
  size_t off;
  if (blk < 2048) {
    src = X; dst = out; off = (size_t)blk * 2048;
  } else {
    int s = (blk - 2048) >> 9;
    src = (s == 0) ? Wq : (s == 1) ? Wk : (s == 2) ? Wv : Wo;
    dst = out + ((size_t)1 << 22) + (size_t)s * (1u << 20);
    off = (size_t)((blk - 2048) & 511) * 2048;
  }
  size_t i = off + (size_t)threadIdx.x * 8;
  float4 v0 = *(const float4*)(src + i);
  float4 v1 = *(const float4*)(src + i + 4);
  uint4 o;
  o.x = packbf2(v0.x, v0.y); o.y = packbf2(v0.z, v0.w);
  o.z = packbf2(v1.x, v1.y); o.w = packbf2(v1.z, v1.w);
  *(uint4*)(dst + i) = o;
}

// ---------------- fused QKV projection, 128x128, XCD-swizzled ----------------
// grid 768 (1D). XCD x (= blockIdx%8) owns m-tiles [ (x&3)*8, +8 ) and
// n-tiles [ (x>>2)*12, +12 ) — per-XCD working set 2MB X + 3MB W in L2.
__global__ __launch_bounds__(256) void gemm_qkv(
    const unsigned short* __restrict__ Xb, const unsigned short* __restrict__ Wb,
    unsigned short* __restrict__ Qb, unsigned short* __restrict__ Kb,
    unsigned short* __restrict__ VT) {
  __shared__ __align__(16) unsigned short Al[128 * 32];
  __shared__ __align__(16) unsigned short Bl[128 * 32];
  const int lin = blockIdx.x;
  const int xcd = lin & 7, sblk = lin >> 3;       // sblk 0..95
  const int m0 = ((xcd & 3) * 8 + (sblk & 7)) * 128;
  const int n0g = ((xcd >> 2) * 12 + (sblk >> 3)) * 128;
  const int sel = n0g >> 10;
  const int tid = threadIdx.x;
  const int w = tid >> 6, lane = tid & 63;
  const int c = lane & 15, quad = lane >> 4;
  const int wm = (w & 1) * 64, wn = (w >> 1) * 64;

  f32x4 zero = {0.f, 0.f, 0.f, 0.f};
  f32x4 acc[4][4];
#pragma unroll
  for (int i = 0; i < 4; ++i)
#pragma unroll
    for (int j = 0; j < 4; ++j) acc[i][j] = zero;

  const int srow = w * 32 + (lane >> 2);
  const int scol = (lane & 3) * 8;
  const unsigned short* gA = Xb + (size_t)(m0 + srow) * DIMN + scol;
  const unsigned short* gB = Wb + (size_t)(n0g + srow) * DIMN + scol;
  unsigned short* lA0 = Al + (w * 32) * 32;
  unsigned short* lA1 = Al + (w * 32 + 16) * 32;
  unsigned short* lB0 = Bl + (w * 32) * 32;
  unsigned short* lB1 = Bl + (w * 32 + 16) * 32;

  for (int k0 = 0; k0 < DIMN; k0 += 32) {
    __syncthreads();
    gld16(gA + k0, lA0);
    gld16(gA + k0 + 16 * DIMN, lA1);
    gld16(gB + k0, lB0);
    gld16(gB + k0 + 16 * DIMN, lB1);
    __syncthreads();
    s16x8 a[4], b[4];
#pragma unroll
    for (int i = 0; i < 4; ++i)
      a[i] = *(const s16x8*)&Al[(wm + i * 16 + c) * 32 + quad * 8];
#pragma unroll
    for (int j = 0; j < 4; ++j)
      b[j] = *(const s16x8*)&Bl[(wn + j * 16 + c) * 32 + quad * 8];
    if (sel != 2) {
#pragma unroll
      for (int i = 0; i < 4; ++i)
#pragma unroll
        for (int j = 0; j < 4; ++j)  // swapped -> C^T (4 consecutive d / lane)
          acc[i][j] = __builtin_amdgcn_mfma_f32_16x16x32_bf16(b[j], a[i], acc[i][j], 0, 0, 0);
    } else {
#pragma unroll
      for (int i = 0; i < 4; ++i)
#pragma unroll
        for (int j = 0; j < 4; ++j)  // normal (4 consecutive seq / lane)
          acc[i][j] = __builtin_amdgcn_mfma_f32_16x16x32_bf16(a[i], b[j], acc[i][j], 0, 0, 0);
    }
  }

  const int n0 = n0g & 1023;
  if (sel != 2) {
    // C^T: row = n (d), col = seq. 8B packed stores, layout [B,H,L,D].
    unsigned short* Out = (sel == 0) ? Qb : Kb;
    const float scale = (sel == 0) ? QSCALE : 1.0f;
    const int bi = (m0 + wm) >> 11;
#pragma unroll
    for (int i = 0; i < 4; ++i) {
      const int li = (m0 + wm + i * 16 + c) & 2047;
#pragma unroll
      for (int j = 0; j < 4; ++j) {
        const int nq = n0 + wn + j * 16 + quad * 4;
        const int h = nq >> 6, d = nq & 63;
        uint2 st;
        st.x = packbf2(acc[i][j][0] * scale, acc[i][j][1] * scale);
        st.y = packbf2(acc[i][j][2] * scale, acc[i][j][3] * scale);
        *(uint2*)&Out[(((size_t)bi * NH + h) * LL + li) * HD + d] = st;
      }
    }
  } else {
    // normal C: row = seq, col = n (d). 8B packed stores, layout [B,H,D,L]
    // with vpos permutation per 128-seq group (keeps low 2 bits -> contiguous).
    const int bi = m0 >> 11;
    const int mlo = m0 & 2047;
#pragma unroll
    for (int i = 0; i < 4; ++i) {
      const int pos = mlo + vpos(wm + i * 16 + quad * 4);
#pragma unroll
      for (int j = 0; j < 4; ++j) {
        const int nv = n0 + wn + j * 16 + c;
        const int h = nv >> 6, d = nv & 63;
        uint2 st;
        st.x = packbf2(acc[i][j][0], acc[i][j][1]);
        st.y = packbf2(acc[i][j][2], acc[i][j][3]);
        *(uint2*)&VT[(((size_t)bi * NH + h) * HD + d) * LL + pos] = st;
      }
    }
  }
}

// ---------------- output projection, 128x64, XCD-swizzled ----------------
// grid 512 (1D). XCD x owns m-tiles {x, x+8, x+16, x+24} x all 16 n-tiles:
// working set 1MB A + 2MB Wo per XCD.
__global__ __launch_bounds__(256) void gemm_o(
    const unsigned short* __restrict__ A, const unsigned short* __restrict__ Wob,
    float* __restrict__ Out) {
  __shared__ __align__(16) unsigned short Al[128 * 32];
  __shared__ __align__(16) unsigned short Bl[64 * 32];
  const int lin = blockIdx.x;
  const int xcd = lin & 7, sblk = lin >> 3;       // sblk 0..63
  const int m0 = ((sblk >> 4) * 8 + xcd) * 128;
  const int n0 = (sblk & 15) * 64;
  const int tid = threadIdx.x;
  const int w = tid >> 6, lane = tid & 63;
  const int c = lane & 15, quad = lane >> 4;
  const int wm = (w & 1) * 64, wn = (w >> 1) * 32;

  f32x4 zero = {0.f, 0.f, 0.f, 0.f};
  f32x4 acc[4][2];
#pragma unroll
  for (int i = 0; i < 4; ++i)
#pragma unroll
    for (int j = 0; j < 2; ++j) acc[i][j] = zero;

  const int srow = w * 32 + (lane >> 2);
  const int brow = w * 16 + (lane >> 2);
  const int scol = (lane & 3) * 8;
  const unsigned short* gA = A + (size_t)(m0 + srow) * DIMN + scol;
  const unsigned short* gB = Wob + (size_t)(n0 + brow) * DIMN + scol;
  unsigned short* lA0 = Al + (w * 32) * 32;
  unsigned short* lA1 = Al + (w * 32 + 16) * 32;
  unsigned short* lB0 = Bl + (w * 16) * 32;

  for (int k0 = 0; k0 < DIMN; k0 += 32) {
    __syncthreads();
    gld16(gA + k0, lA0);
    gld16(gA + k0 + 16 * DIMN, lA1);
    gld16(gB + k0, lB0);
    __syncthreads();
    s16x8 a[4], b[2];
#pragma unroll
    for (int i = 0; i < 4; ++i)
      a[i] = *(const s16x8*)&Al[(wm + i * 16 + c) * 32 + quad * 8];
#pragma unroll
    for (int j = 0; j < 2; ++j)
      b[j] = *(const s16x8*)&Bl[(wn + j * 16 + c) * 32 + quad * 8];
#pragma unroll
    for (int i = 0; i < 4; ++i)
#pragma unroll
      for (int j = 0; j < 2; ++j)
        acc[i][j] = __builtin_amdgcn_mfma_f32_16x16x32_bf16(a[i], b[j], acc[i][j], 0, 0, 0);
  }

#pragma unroll
  for (int i = 0; i < 4; ++i)
#pragma unroll
    for (int j = 0; j < 2; ++j)
#pragma unroll
      for (int r = 0; r < 4; ++r)
        Out[(size_t)(m0 + wm + i * 16 + quad * 4 + r) * DIMN + n0 + wn + j * 16 + c] =
            acc[i][j][r];
}

// ---------------- flash attention, 8 waves x 16 q-rows, XCD-swizzled ----------------
// grid 512 (1D). XCD x owns bh in {x, x+8, x+16, x+24} x all 16 q-blocks:
// per-XCD K/V working set = 4 x 512KB = 2MB in L2.
__global__ __launch_bounds__(512) void attn6(
    const unsigned short* __restrict__ Qb, const unsigned short* __restrict__ Kb,
    const unsigned short* __restrict__ VT, unsigned short* __restrict__ AO) {
  __shared__ __align__(16) unsigned short Kl[2 * 128 * 64];   // 32 KB
  __shared__ __align__(16) unsigned short Vtl[2 * 64 * 128];  // 32 KB

  const int lin = blockIdx.x;
  const int xcd = lin & 7, sblk = lin >> 3;       // sblk 0..63
  const int bh = (sblk >> 4) * 8 + xcd;
  const int qi = sblk & 15;
  const int tid = threadIdx.x;
  const int w = tid >> 6, lane = tid & 63;
  const int c = lane & 15, quad = lane >> 4;
  const int q0 = qi * 128 + w * 16;

  const unsigned short* Qh = Qb + (size_t)bh * LL * HD;
  const unsigned short* Kh = Kb + (size_t)bh * LL * HD;
  const unsigned short* Vh = VT + (size_t)bh * HD * LL;   // [d][l], permuted

  s16x8 qf0 = *(const s16x8*)(Qh + (size_t)(q0 + c) * HD + quad * 8);
  s16x8 qf1 = *(const s16x8*)(Qh + (size_t)(q0 + c) * HD + 32 + quad * 8);

  f32x4 zero = {0.f, 0.f, 0.f, 0.f};
  f32x4 o[4];
  float lsum = 0.f;
#pragma unroll
  for (int dc = 0; dc < 4; ++dc) o[dc] = zero;

  const int l8 = lane >> 3, p8 = lane & 7;
  const unsigned short* gK = Kh + (size_t)(w * 16 + l8) * HD + ((p8 ^ l8) * 8);
  const int l16 = lane >> 4, p16 = lane & 15;
  const int vr0 = w * 8 + l16;
  const int vr1 = w * 8 + 4 + l16;
  const unsigned short* gV0 = Vh + (size_t)vr0 * LL + ((p16 ^ (vr0 & 15)) * 8);
  const unsigned short* gV1 = Vh + (size_t)vr1 * LL + ((p16 ^ (vr1 & 15)) * 8);

  const int kpa = (quad ^ (c & 7)) * 8;
  const int kpb = ((quad + 4) ^ (c & 7)) * 8;

#define STAGE(buf, k0)                                                        \
  do {                                                                        \
    unsigned short* lK_ = Kl + (buf) * (128 * 64) + (w * 16) * 64;            \
    unsigned short* lV_ = Vtl + (buf) * (64 * 128) + (w * 8) * 128;           \
    gld16(gK + (size_t)(k0) * HD, lK_);                                       \
    gld16(gK + (size_t)((k0) + 8) * HD, lK_ + 8 * 64);                        \
    gld16(gV0 + (k0), lV_);                                                   \
    gld16(gV1 + (k0), lV_ + 4 * 128);                                         \
  } while (0)

  STAGE(0, 0);

  for (int it = 0; it < LL / 128; ++it) {
    __syncthreads();
    if (it + 1 < LL / 128) STAGE((it + 1) & 1, (it + 1) * 128);
    const unsigned short* Kt = Kl + (it & 1) * (128 * 64);
    const unsigned short* Vt = Vtl + (it & 1) * (64 * 128);

#pragma unroll
    for (int g = 0; g < 2; ++g) {
      f32x4 s[4];
#pragma unroll
      for (int t4 = 0; t4 < 4; ++t4) {
        const unsigned short* kr = Kt + ((g * 4 + t4) * 16 + c) * 64;
        s16x8 kfa = *(const s16x8*)(kr + kpa);
        s16x8 kfb = *(const s16x8*)(kr + kpb);
        s[t4] = __builtin_amdgcn_mfma_f32_16x16x32_bf16(kfa, qf0, zero, 0, 0, 0);
        s[t4] = __builtin_amdgcn_mfma_f32_16x16x32_bf16(kfb, qf1, s[t4], 0, 0, 0);
      }
      float p[4][4];
      float acc_l = 0.f;
#pragma unroll
      for (int t4 = 0; t4 < 4; ++t4)
#pragma unroll
        for (int r = 0; r < 4; ++r) {
          float e = xexp2(s[t4][r]);
          p[t4][r] = e;
          acc_l += e;
        }
      lsum += acc_l;
#pragma unroll
      for (int kh = 0; kh < 2; ++kh) {
        const int kk = g * 2 + kh;
        unsigned pu[4];
        pu[0] = __builtin_amdgcn_perm(__float_as_uint(p[2 * kh][1]),
                                      __float_as_uint(p[2 * kh][0]), 0x07060302u);
        pu[1] = __builtin_amdgcn_perm(__float_as_uint(p[2 * kh][3]),
                                      __float_as_uint(p[2 * kh][2]), 0x07060302u);
        pu[2] = __builtin_amdgcn_perm(__float_as_uint(p[2 * kh + 1][1]),
                                      __float_as_uint(p[2 * kh + 1][0]), 0x07060302u);
        pu[3] = __builtin_amdgcn_perm(__float_as_uint(p[2 * kh + 1][3]),
                                      __float_as_uint(p[2 * kh + 1][2]), 0x07060302u);
        s16x8 pf = *(const s16x8*)pu;
#pragma unroll
        for (int dc = 0; dc < 4; ++dc) {
          s16x8 vf = *(const s16x8*)(Vt + (dc * 16 + c) * 128 + (((kk * 4 + quad) ^ c) * 8));
          o[dc] = __builtin_amdgcn_mfma_f32_16x16x32_bf16(vf, pf, o[dc], 0, 0, 0);
        }
      }
    }
  }
#undef STAGE

  const int bi = bh >> 4, h = bh & 15;
  float l = lsum;
  l += __shfl_xor(l, 16);
  l += __shfl_xor(l, 32);
  float inv = 1.0f / l;
  unsigned short* dst = AO + ((size_t)bi * LL + q0 + c) * DIMN + h * HD + quad * 4;
#pragma unroll
  for (int dc = 0; dc < 4; ++dc) {
    uint2 st;
    st.x = packbf2(o[dc][0] * inv, o[dc][1] * inv);
    st.y = packbf2(o[dc][2] * inv, o[dc][3] * inv);
    *(uint2*)(dst + dc * 16) = st;
  }
}

// ---------------- fp32 fallback path (1-wave GEMMs), ws < 48 MiB ----------------
__global__ __launch_bounds__(64) void qkv_proj_f(
    const float* __restrict__ X, const float* __restrict__ Wq,
    const float* __restrict__ Wk, const float* __restrict__ Wv,
    unsigned short* __restrict__ Qb, unsigned short* __restrict__ Kb,
    unsigned short* __restrict__ VT) {
  const int m0 = blockIdx.x * 64;
  const int n0g = blockIdx.y * 64;
  const int sel = n0g >> 10;
  const int n0 = n0g & 1023;
  const float* W = (sel == 0) ? Wq : (sel == 1) ? Wk : Wv;
  const int lane = threadIdx.x;
  const int c = lane & 15, quad = lane >> 4;

  f32x4 zero = {0.f, 0.f, 0.f, 0.f};
  f32x4 acc[4][4];
#pragma unroll
  for (int i = 0; i < 4; ++i)
#pragma unroll
    for (int j = 0; j < 4; ++j) acc[i][j] = zero;

  const float* ab = X + (size_t)(m0 + c) * DIMN + quad * 8;
  const float* bb = W + (size_t)(n0 + c) * DIMN + quad * 8;

  for (int k0 = 0; k0 < DIMN; k0 += 32) {
    s16x8 a[4], b[4];
#pragma unroll
    for (int i = 0; i < 4; ++i) {
      const float* pp = ab + i * 16 * DIMN + k0;
      a[i] = cvt8(*(const float4*)pp, *(const float4*)(pp + 4));
    }
#pragma unroll
    for (int j = 0; j < 4; ++j) {
      const float* pp = bb + j * 16 * DIMN + k0;
      b[j] = cvt8(*(const float4*)pp, *(const float4*)(pp + 4));
    }
    if (sel != 2) {
#pragma unroll
      for (int i = 0; i < 4; ++i)
#pragma unroll
        for (int j = 0; j < 4; ++j)
          acc[i][j] = __builtin_amdgcn_mfma_f32_16x16x32_bf16(a[i], b[j], acc[i][j], 0, 0, 0);
    } else {
#pragma unroll
      for (int i = 0; i < 4; ++i)
#pragma unroll
        for (int j = 0; j < 4; ++j)
          acc[i][j] = __builtin_amdgcn_mfma_f32_16x16x32_bf16(b[j], a[i], acc[i][j], 0, 0, 0);
    }
  }

  if (sel != 2) {
    unsigned short* Out = (sel == 0) ? Qb : Kb;
    const float scale = (sel == 0) ? QSCALE : 1.0f;
#pragma unroll
    for (int i = 0; i < 4; ++i)
#pragma unroll
      for (int j = 0; j < 4; ++j)
#pragma unroll
        for (int r = 0; r < 4; ++r) {
          int row = m0 + i * 16 + quad * 4 + r;
          int nl = n0 + j * 16 + c;
          int bi = row >> 11, li = row & 2047;
          int h = nl >> 6, d = nl & 63;
          Out[(((size_t)bi * NH + h) * LL + li) * HD + d] = f2bf(acc[i][j][r] * scale);
        }
  } else {
#pragma unroll
    for (int i = 0; i < 4; ++i) {
#pragma unroll
      for (int j = 0; j < 4; ++j)
#pragma unroll
        for (int r = 0; r < 4; ++r) {
          int n = n0 + j * 16 + quad * 4 + r;
          int s128 = (m0 & 64) + i * 16 + c;
          int m = (m0 & ~127) + vpos(s128);
          int h = n >> 6, d = n & 63;
          int bi = m0 >> 11;
          VT[(((size_t)bi * NH + h) * HD + d) * LL + (m & 2047)] = f2bf(acc[i][j][r]);
        }
    }
  }
}

__global__ __launch_bounds__(64) void o_proj_f(
    const unsigned short* __restrict__ A, const float* __restrict__ Wo,
    float* __restrict__ Out) {
  const int m0 = blockIdx.x * 64, n0 = blockIdx.y * 64;
  const int lane = threadIdx.x;
  const int c = lane & 15, quad = lane >> 4;

  f32x4 zero = {0.f, 0.f, 0.f, 0.f};
  f32x4 acc[4][4];
#pragma unroll
  for (int i = 0; i < 4; ++i)
#pragma unroll
    for (int j = 0; j < 4; ++j) acc[i][j] = zero;

  const unsigned short* ab = A + (size_t)(m0 + c) * DIMN + quad * 8;
  const float* bb = Wo + (size_t)(n0 + c) * DIMN + quad * 8;

  for (int k0 = 0; k0 < DIMN; k0 += 32) {
    s16x8 a[4], b[4];
#pragma unroll
    for (int i = 0; i < 4; ++i) a[i] = *(const s16x8*)(ab + i * 16 * DIMN + k0);
#pragma unroll
    for (int j = 0; j < 4; ++j) {
      const float* pp = bb + j * 16 * DIMN + k0;
      b[j] = cvt8(*(const float4*)pp, *(const float4*)(pp + 4));
    }
#pragma unroll
    for (int i = 0; i < 4; ++i)
#pragma unroll
      for (int j = 0; j < 4; ++j)
        acc[i][j] = __builtin_amdgcn_mfma_f32_16x16x32_bf16(a[i], b[j], acc[i][j], 0, 0, 0);
  }

#pragma unroll
  for (int i = 0; i < 4; ++i)
#pragma unroll
    for (int j = 0; j < 4; ++j)
#pragma unroll
      for (int r = 0; r < 4; ++r)
        Out[(size_t)(m0 + i * 16 + quad * 4 + r) * DIMN + n0 + j * 16 + c] = acc[i][j][r];
}

extern "C" void kernel_launch(void* const* d_in, const int* in_sizes, int n_in,
                              void* d_out, int out_size, void* d_ws, size_t ws_size,
                              hipStream_t stream) {
  const float* X = (const float*)d_in[0];
  const float* Wq = (const float*)d_in[1];
  const float* Wk = (const float*)d_in[2];
  const float* Wv = (const float*)d_in[3];
  const float* Wo = (const float*)d_in[4];
  float* Out = (float*)d_out;

  const size_t M1 = (size_t)1 << 20;
  unsigned short* ws16 = (unsigned short*)d_ws;

  if (ws_size >= (size_t)48 * 1024 * 1024) {
    unsigned short* Xb = ws16;            // 4M elems
    unsigned short* Wb = ws16 + 4 * M1;   // 4 x 1M (Wq,Wk,Wv,Wo contiguous)
    unsigned short* Qb = ws16 + 8 * M1;
    unsigned short* Kb = ws16 + 12 * M1;
    unsigned short* VT = ws16 + 16 * M1;
    unsigned short* AO = ws16 + 20 * M1;
    cvt_all<<<4096, 256, 0, stream>>>(X, Wq, Wk, Wv, Wo, ws16);
    gemm_qkv<<<768, 256, 0, stream>>>(Xb, Wb, Qb, Kb, VT);
    attn6<<<512, 512, 0, stream>>>(Qb, Kb, VT, AO);
    gemm_o<<<512, 256, 0, stream>>>(AO, Wb + 3 * M1, Out);
  } else {
    unsigned short* Qb = ws16;
    unsigned short* Kb = ws16 + 4 * M1;
    unsigned short* VT = ws16 + 8 * M1;
    unsigned short* AO = ws16 + 12 * M1;
    qkv_proj_f<<<dim3(64, 48), 64, 0, stream>>>(X, Wq, Wk, Wv, Qb, Kb, VT);
    attn6<<<512, 512, 0, stream>>>(Qb, Kb, VT, AO);
    o_proj_f<<<dim3(64, 16), 64, 0, stream>>>(AO, Wo, Out);
  }
}

// Round 11
// 178.559 us; speedup vs baseline: 1.1257x; 1.0406x over previous
//
#include <hip/hip_runtime.h>

// MultiHeadAttention: out = softmax((XWq^T)(XWk^T)^T / 8) (XWv^T) Wo^T
// B=2, L=2048, DIM=1024, H=16, D=64. fp32 in/out, bf16 MFMA compute.
//
// R11: GEMMs move to BK=64 (16 K-iters, 32 MFMA per barrier-pair — halves
//      barrier drains) using attn6's hardware-proven 64-short-row XOR swizzle
//      for both staging and fragment reads. Registers kept at R9 level by
//      loading fragments per k-half. attn6 / cvt_all / XCD swizzle unchanged.

#define DIMN 1024
#define NH 16
#define HD 64
#define BB 2
#define LL 2048

typedef float f32x4 __attribute__((ext_vector_type(4)));
typedef short s16x8 __attribute__((ext_vector_type(8)));

#define QSCALE 0.18033688011112042f  // log2(e)/8, folds softmax exp2 domain

static __device__ __forceinline__ unsigned short f2bf(float f) {
  unsigned u = __float_as_uint(f);
  u += 0x7fffu + ((u >> 16) & 1u);   // RNE
  return (unsigned short)(u >> 16);
}
static __device__ __forceinline__ unsigned packbf2(float lo, float hi) {
  return (unsigned)f2bf(lo) | ((unsigned)f2bf(hi) << 16);
}
static __device__ __forceinline__ float xexp2(float x) {
#if __has_builtin(__builtin_amdgcn_exp2f)
  return __builtin_amdgcn_exp2f(x);
#else
  return exp2f(x);
#endif
}
static __device__ __forceinline__ s16x8 cvt8(float4 a, float4 b) {
  s16x8 r;
  r[0] = (short)f2bf(a.x); r[1] = (short)f2bf(a.y);
  r[2] = (short)f2bf(a.z); r[3] = (short)f2bf(a.w);
  r[4] = (short)f2bf(b.x); r[5] = (short)f2bf(b.y);
  r[6] = (short)f2bf(b.z); r[7] = (short)f2bf(b.w);
  return r;
}
// async global->LDS, 16B/lane; LDS dest is wave-uniform base + lane*16
static __device__ __forceinline__ void gld16(const unsigned short* g,
                                             unsigned short* l) {
#if __has_builtin(__builtin_amdgcn_global_load_lds)
  __builtin_amdgcn_global_load_lds(
      (const __attribute__((address_space(1))) void*)g,
      (__attribute__((address_space(3))) void*)l, 16, 0, 0);
#else
  ((uint4*)l)[threadIdx.x & 63] = ((const uint4*)g)[0];
#endif
}

// V storage permutation within each 128-seq group (bits of s):
// pos = b6*64 + b5*32 + (bits3:2)*8 + bit4*4 + bits1:0  — keeps low 2 bits.
static __device__ __forceinline__ int vpos(int s128) {
  return (s128 & 0x60) | ((s128 & 0x0C) << 1) | ((s128 & 0x10) >> 2) | (s128 & 3);
}

// ---------------- fp32 -> bf16 pre-convert (X + 4 weights) ----------------
__global__ __launch_bounds__(256) void cvt_all(
    const float* __restrict__ X, const float* __restrict__ Wq,
    const float* __restrict__ Wk, const float* __restrict__ Wv,
    const float* __restrict__ Wo, unsigned short* __restrict__ out) {
  const int blk = blockIdx.x;
  const float* src;
  unsigned short* dst;
  size_t off;
  if (blk < 2048) {
    src = X; dst = out; off = (size_t)blk * 2048;
  } else {
    int s = (blk - 2048) >> 9;
    src = (s == 0) ? Wq : (s == 1) ? Wk : (s == 2) ? Wv : Wo;
    dst = out + ((size_t)1 << 22) + (size_t)s * (1u << 20);
    off = (size_t)((blk - 2048) & 511) * 2048;
  }
  size_t i = off + (size_t)threadIdx.x * 8;
  float4 v0 = *(const float4*)(src + i);
  float4 v1 = *(const float4*)(src + i + 4);
  uint4 o;
  o.x = packbf2(v0.x, v0.y); o.y = packbf2(v0.z, v0.w);
  o.z = packbf2(v1.x, v1.y); o.w = packbf2(v1.z, v1.w);
  *(uint4*)(dst + i) = o;
}

// ---------------- fused QKV projection, 128x128, BK=64 ----------------
// grid 768 (1D, XCD-swizzled). Rows in LDS are 64 shorts (128 B), chunk-
// swizzled: phys slot p of row r holds logical chunk p ^ (r&7).
__global__ __launch_bounds__(256) void gemm_qkv(
    const unsigned short* __restrict__ Xb, const unsigned short* __restrict__ Wb,
    unsigned short* __restrict__ Qb, unsigned short* __restrict__ Kb,
    unsigned short* __restrict__ VT) {
  __shared__ __align__(16) unsigned short Al[128 * 64];   // 16 KB
  __shared__ __align__(16) unsigned short Bl[128 * 64];   // 16 KB
  const int lin = blockIdx.x;
  const int xcd = lin & 7, sblk = lin >> 3;       // sblk 0..95
  const int m0 = ((xcd & 3) * 8 + (sblk & 7)) * 128;
  const int n0g = ((xcd >> 2) * 12 + (sblk >> 3)) * 128;
  const int sel = n0g >> 10;
  const int tid = threadIdx.x;
  const int w = tid >> 6, lane = tid & 63;
  const int c = lane & 15, quad = lane >> 4;
  const int wm = (w & 1) * 64, wn = (w >> 1) * 64;

  f32x4 zero = {0.f, 0.f, 0.f, 0.f};
  f32x4 acc[4][4];
#pragma unroll
  for (int i = 0; i < 4; ++i)
#pragma unroll
    for (int j = 0; j < 4; ++j) acc[i][j] = zero;

  // staging: wave covers 8 rows per gld16 (8 lanes x 16B per row);
  // source column carries the chunk swizzle (attn6 K pattern).
  const int l8 = lane >> 3, p8 = lane & 7;
  const unsigned short* gA = Xb + (size_t)(m0 + w * 8 + l8) * DIMN + ((p8 ^ l8) * 8);
  const unsigned short* gB = Wb + (size_t)(n0g + w * 8 + l8) * DIMN + ((p8 ^ l8) * 8);
  unsigned short* lA = Al + (w * 8) * 64;
  unsigned short* lB = Bl + (w * 8) * 64;
  const int c7 = c & 7;

  for (int k0 = 0; k0 < DIMN; k0 += 64) {
    __syncthreads();
#pragma unroll
    for (int r = 0; r < 4; ++r) {
      gld16(gA + k0 + (size_t)(r * 32) * DIMN, lA + r * 32 * 64);
      gld16(gB + k0 + (size_t)(r * 32) * DIMN, lB + r * 32 * 64);
    }
    __syncthreads();
#pragma unroll
    for (int f = 0; f < 2; ++f) {
      const int rd = ((f * 4 + quad) ^ c7) * 8;
      s16x8 a[4], b[4];
#pragma unroll
      for (int i = 0; i < 4; ++i)
        a[i] = *(const s16x8*)&Al[(wm + i * 16 + c) * 64 + rd];
#pragma unroll
      for (int j = 0; j < 4; ++j)
        b[j] = *(const s16x8*)&Bl[(wn + j * 16 + c) * 64 + rd];
      if (sel != 2) {
#pragma unroll
        for (int i = 0; i < 4; ++i)
#pragma unroll
          for (int j = 0; j < 4; ++j)  // swapped -> C^T (4 consecutive d / lane)
            acc[i][j] = __builtin_amdgcn_mfma_f32_16x16x32_bf16(b[j], a[i], acc[i][j], 0, 0, 0);
      } else {
#pragma unroll
        for (int i = 0; i < 4; ++i)
#pragma unroll
          for (int j = 0; j < 4; ++j)  // normal (4 consecutive seq / lane)
            acc[i][j] = __builtin_amdgcn_mfma_f32_16x16x32_bf16(a[i], b[j], acc[i][j], 0, 0, 0);
      }
    }
  }

  const int n0 = n0g & 1023;
  if (sel != 2) {
    // C^T: row = n (d), col = seq. 8B packed stores, layout [B,H,L,D].
    unsigned short* Out = (sel == 0) ? Qb : Kb;
    const float scale = (sel == 0) ? QSCALE : 1.0f;
    const int bi = (m0 + wm) >> 11;
#pragma unroll
    for (int i = 0; i < 4; ++i) {
      const int li = (m0 + wm + i * 16 + c) & 2047;
#pragma unroll
      for (int j = 0; j < 4; ++j) {
        const int nq = n0 + wn + j * 16 + quad * 4;
        const int h = nq >> 6, d = nq & 63;
        uint2 st;
        st.x = packbf2(acc[i][j][0] * scale, acc[i][j][1] * scale);
        st.y = packbf2(acc[i][j][2] * scale, acc[i][j][3] * scale);
        *(uint2*)&Out[(((size_t)bi * NH + h) * LL + li) * HD + d] = st;
      }
    }
  } else {
    // normal C: row = seq, col = n (d). 8B packed stores, layout [B,H,D,L]
    // with vpos permutation per 128-seq group (keeps low 2 bits -> contiguous).
    const int bi = m0 >> 11;
    const int mlo = m0 & 2047;
#pragma unroll
    for (int i = 0; i < 4; ++i) {
      const int pos = mlo + vpos(wm + i * 16 + quad * 4);
#pragma unroll
      for (int j = 0; j < 4; ++j) {
        const int nv = n0 + wn + j * 16 + c;
        const int h = nv >> 6, d = nv & 63;
        uint2 st;
        st.x = packbf2(acc[i][j][0], acc[i][j][1]);
        st.y = packbf2(acc[i][j][2], acc[i][j][3]);
        *(uint2*)&VT[(((size_t)bi * NH + h) * HD + d) * LL + pos] = st;
      }
    }
  }
}

// ---------------- output projection, 128x64, BK=64 ----------------
// grid 512 (1D, XCD-swizzled). Same swizzled 64-short-row LDS tiles.
__global__ __launch_bounds__(256) void gemm_o(
    const unsigned short* __restrict__ A, const unsigned short* __restrict__ Wob,
    float* __restrict__ Out) {
  __shared__ __align__(16) unsigned short Al[128 * 64];   // 16 KB
  __shared__ __align__(16) unsigned short Bl[64 * 64];    // 8 KB
  const int lin = blockIdx.x;
  const int xcd = lin & 7, sblk = lin >> 3;       // sblk 0..63
  const int m0 = ((sblk >> 4) * 8 + xcd) * 128;
  const int n0 = (sblk & 15) * 64;
  const int tid = threadIdx.x;
  const int w = tid >> 6, lane = tid & 63;
  const int c = lane & 15, quad = lane >> 4;
  const int wm = (w & 1) * 64, wn = (w >> 1) * 32;

  f32x4 zero = {0.f, 0.f, 0.f, 0.f};
  f32x4 acc[4][2];
#pragma unroll
  for (int i = 0; i < 4; ++i)
#pragma unroll
    for (int j = 0; j < 2; ++j) acc[i][j] = zero;

  const int l8 = lane >> 3, p8 = lane & 7;
  const unsigned short* gA = A + (size_t)(m0 + w * 8 + l8) * DIMN + ((p8 ^ l8) * 8);
  const unsigned short* gB = Wob + (size_t)(n0 + w * 8 + l8) * DIMN + ((p8 ^ l8) * 8);
  unsigned short* lA = Al + (w * 8) * 64;
  unsigned short* lB = Bl + (w * 8) * 64;
  const int c7 = c & 7;

  for (int k0 = 0; k0 < DIMN; k0 += 64) {
    __syncthreads();
#pragma unroll
    for (int r = 0; r < 4; ++r)
      gld16(gA + k0 + (size_t)(r * 32) * DIMN, lA + r * 32 * 64);
#pragma unroll
    for (int r = 0; r < 2; ++r)
      gld16(gB + k0 + (size_t)(r * 32) * DIMN, lB + r * 32 * 64);
    __syncthreads();
#pragma unroll
    for (int f = 0; f < 2; ++f) {
      const int rd = ((f * 4 + quad) ^ c7) * 8;
      s16x8 a[4], b[2];
#pragma unroll
      for (int i = 0; i < 4; ++i)
        a[i] = *(const s16x8*)&Al[(wm + i * 16 + c) * 64 + rd];
#pragma unroll
      for (int j = 0; j < 2; ++j)
        b[j] = *(const s16x8*)&Bl[(wn + j * 16 + c) * 64 + rd];
#pragma unroll
      for (int i = 0; i < 4; ++i)
#pragma unroll
        for (int j = 0; j < 2; ++j)
          acc[i][j] = __builtin_amdgcn_mfma_f32_16x16x32_bf16(a[i], b[j], acc[i][j], 0, 0, 0);
    }
  }

#pragma unroll
  for (int i = 0; i < 4; ++i)
#pragma unroll
    for (int j = 0; j < 2; ++j)
#pragma unroll
      for (int r = 0; r < 4; ++r)
        Out[(size_t)(m0 + wm + i * 16 + quad * 4 + r) * DIMN + n0 + wn + j * 16 + c] =
            acc[i][j][r];
}

// ---------------- flash attention, 8 waves x 16 q-rows (unchanged R10) ----------------
__global__ __launch_bounds__(512) void attn6(
    const unsigned short* __restrict__ Qb, const unsigned short* __restrict__ Kb,
    const unsigned short* __restrict__ VT, unsigned short* __restrict__ AO) {
  __shared__ __align__(16) unsigned short Kl[2 * 128 * 64];   // 32 KB
  __shared__ __align__(16) unsigned short Vtl[2 * 64 * 128];  // 32 KB

  const int lin = blockIdx.x;
  const int xcd = lin & 7, sblk = lin >> 3;       // sblk 0..63
  const int bh = (sblk >> 4) * 8 + xcd;
  const int qi = sblk & 15;
  const int tid = threadIdx.x;
  const int w = tid >> 6, lane = tid & 63;
  const int c = lane & 15, quad = lane >> 4;
  const int q0 = qi * 128 + w * 16;

  const unsigned short* Qh = Qb + (size_t)bh * LL * HD;
  const unsigned short* Kh = Kb + (size_t)bh * LL * HD;
  const unsigned short* Vh = VT + (size_t)bh * HD * LL;   // [d][l], permuted

  s16x8 qf0 = *(const s16x8*)(Qh + (size_t)(q0 + c) * HD + quad * 8);
  s16x8 qf1 = *(const s16x8*)(Qh + (size_t)(q0 + c) * HD + 32 + quad * 8);

  f32x4 zero = {0.f, 0.f, 0.f, 0.f};
  f32x4 o[4];
  float lsum = 0.f;
#pragma unroll
  for (int dc = 0; dc < 4; ++dc) o[dc] = zero;

  const int l8 = lane >> 3, p8 = lane & 7;
  const unsigned short* gK = Kh + (size_t)(w * 16 + l8) * HD + ((p8 ^ l8) * 8);
  const int l16 = lane >> 4, p16 = lane & 15;
  const int vr0 = w * 8 + l16;
  const int vr1 = w * 8 + 4 + l16;
  const unsigned short* gV0 = Vh + (size_t)vr0 * LL + ((p16 ^ (vr0 & 15)) * 8);
  const unsigned short* gV1 = Vh + (size_t)vr1 * LL + ((p16 ^ (vr1 & 15)) * 8);

  const int kpa = (quad ^ (c & 7)) * 8;
  const int kpb = ((quad + 4) ^ (c & 7)) * 8;

#define STAGE(buf, k0)                                                        \
  do {                                                                        \
    unsigned short* lK_ = Kl + (buf) * (128 * 64) + (w * 16) * 64;            \
    unsigned short* lV_ = Vtl + (buf) * (64 * 128) + (w * 8) * 128;           \
    gld16(gK + (size_t)(k0) * HD, lK_);                                       \
    gld16(gK + (size_t)((k0) + 8) * HD, lK_ + 8 * 64);                        \
    gld16(gV0 + (k0), lV_);                                                   \
    gld16(gV1 + (k0), lV_ + 4 * 128);                                         \
  } while (0)

  STAGE(0, 0);

  for (int it = 0; it < LL / 128; ++it) {
    __syncthreads();
    if (it + 1 < LL / 128) STAGE((it + 1) & 1, (it + 1) * 128);
    const unsigned short* Kt = Kl + (it & 1) * (128 * 64);
    const unsigned short* Vt = Vtl + (it & 1) * (64 * 128);

#pragma unroll
    for (int g = 0; g < 2; ++g) {
      f32x4 s[4];
#pragma unroll
      for (int t4 = 0; t4 < 4; ++t4) {
        const unsigned short* kr = Kt + ((g * 4 + t4) * 16 + c) * 64;
        s16x8 kfa = *(const s16x8*)(kr + kpa);
        s16x8 kfb = *(const s16x8*)(kr + kpb);
        s[t4] = __builtin_amdgcn_mfma_f32_16x16x32_bf16(kfa, qf0, zero, 0, 0, 0);
        s[t4] = __builtin_amdgcn_mfma_f32_16x16x32_bf16(kfb, qf1, s[t4], 0, 0, 0);
      }
      float p[4][4];
      float acc_l = 0.f;
#pragma unroll
      for (int t4 = 0; t4 < 4; ++t4)
#pragma unroll
        for (int r = 0; r < 4; ++r) {
          float e = xexp2(s[t4][r]);
          p[t4][r] = e;
          acc_l += e;
        }
      lsum += acc_l;
#pragma unroll
      for (int kh = 0; kh < 2; ++kh) {
        const int kk = g * 2 + kh;
        unsigned pu[4];
        pu[0] = __builtin_amdgcn_perm(__float_as_uint(p[2 * kh][1]),
                                      __float_as_uint(p[2 * kh][0]), 0x07060302u);
        pu[1] = __builtin_amdgcn_perm(__float_as_uint(p[2 * kh][3]),
                                      __float_as_uint(p[2 * kh][2]), 0x07060302u);
        pu[2] = __builtin_amdgcn_perm(__float_as_uint(p[2 * kh + 1][1]),
                                      __float_as_uint(p[2 * kh + 1][0]), 0x07060302u);
        pu[3] = __builtin_amdgcn_perm(__float_as_uint(p[2 * kh + 1][3]),
                                      __float_as_uint(p[2 * kh + 1][2]), 0x07060302u);
        s16x8 pf = *(const s16x8*)pu;
#pragma unroll
        for (int dc = 0; dc < 4; ++dc) {
          s16x8 vf = *(const s16x8*)(Vt + (dc * 16 + c) * 128 + (((kk * 4 + quad) ^ c) * 8));
          o[dc] = __builtin_amdgcn_mfma_f32_16x16x32_bf16(vf, pf, o[dc], 0, 0, 0);
        }
      }
    }
  }
#undef STAGE

  const int bi = bh >> 4, h = bh & 15;
  float l = lsum;
  l += __shfl_xor(l, 16);
  l += __shfl_xor(l, 32);
  float inv = 1.0f / l;
  unsigned short* dst = AO + ((size_t)bi * LL + q0 + c) * DIMN + h * HD + quad * 4;
#pragma unroll
  for (int dc = 0; dc < 4; ++dc) {
    uint2 st;
    st.x = packbf2(o[dc][0] * inv, o[dc][1] * inv);
    st.y = packbf2(o[dc][2] * inv, o[dc][3] * inv);
    *(uint2*)(dst + dc * 16) = st;
  }
}

// ---------------- fp32 fallback path (1-wave GEMMs), ws < 48 MiB ----------------
__global__ __launch_bounds__(64) void qkv_proj_f(
    const float* __restrict__ X, const float* __restrict__ Wq,
    const float* __restrict__ Wk, const float* __restrict__ Wv,
    unsigned short* __restrict__ Qb, unsigned short* __restrict__ Kb,
    unsigned short* __restrict__ VT) {
  const int m0 = blockIdx.x * 64;
  const int n0g = blockIdx.y * 64;
  const int sel = n0g >> 10;
  const int n0 = n0g & 1023;
  const float* W = (sel == 0) ? Wq : (sel == 1) ? Wk : Wv;
  const int lane = threadIdx.x;
  const int c = lane & 15, quad = lane >> 4;

  f32x4 zero = {0.f, 0.f, 0.f, 0.f};
  f32x4 acc[4][4];
#pragma unroll
  for (int i = 0; i < 4; ++i)
#pragma unroll
    for (int j = 0; j < 4; ++j) acc[i][j] = zero;

  const float* ab = X + (size_t)(m0 + c) * DIMN + quad * 8;
  const float* bb = W + (size_t)(n0 + c) * DIMN + quad * 8;

  for (int k0 = 0; k0 < DIMN; k0 += 32) {
    s16x8 a[4], b[4];
#pragma unroll
    for (int i = 0; i < 4; ++i) {
      const float* pp = ab + i * 16 * DIMN + k0;
      a[i] = cvt8(*(const float4*)pp, *(const float4*)(pp + 4));
    }
#pragma unroll
    for (int j = 0; j < 4; ++j) {
      const float* pp = bb + j * 16 * DIMN + k0;
      b[j] = cvt8(*(const float4*)pp, *(const float4*)(pp + 4));
    }
    if (sel != 2) {
#pragma unroll
      for (int i = 0; i < 4; ++i)
#pragma unroll
        for (int j = 0; j < 4; ++j)
          acc[i][j] = __builtin_amdgcn_mfma_f32_16x16x32_bf16(a[i], b[j], acc[i][j], 0, 0, 0);
    } else {
#pragma unroll
      for (int i = 0; i < 4; ++i)
#pragma unroll
        for (int j = 0; j < 4; ++j)
          acc[i][j] = __builtin_amdgcn_mfma_f32_16x16x32_bf16(b[j], a[i], acc[i][j], 0, 0, 0);
    }
  }

  if (sel != 2) {
    unsigned short* Out = (sel == 0) ? Qb : Kb;
    const float scale = (sel == 0) ? QSCALE : 1.0f;
#pragma unroll
    for (int i = 0; i < 4; ++i)
#pragma unroll
      for (int j = 0; j < 4; ++j)
#pragma unroll
        for (int r = 0; r < 4; ++r) {
          int row = m0 + i * 16 + quad * 4 + r;
          int nl = n0 + j * 16 + c;
          int bi = row >> 11, li = row & 2047;
          int h = nl >> 6, d = nl & 63;
          Out[(((size_t)bi * NH + h) * LL + li) * HD + d] = f2bf(acc[i][j][r] * scale);
        }
  } else {
#pragma unroll
    for (int i = 0; i < 4; ++i) {
#pragma unroll
      for (int j = 0; j < 4; ++j)
#pragma unroll
        for (int r = 0; r < 4; ++r) {
          int n = n0 + j * 16 + quad * 4 + r;
          int s128 = (m0 & 64) + i * 16 + c;
          int m = (m0 & ~127) + vpos(s128);
          int h = n >> 6, d = n & 63;
          int bi = m0 >> 11;
          VT[(((size_t)bi * NH + h) * HD + d) * LL + (m & 2047)] = f2bf(acc[i][j][r]);
        }
    }
  }
}

__global__ __launch_bounds__(64) void o_proj_f(
    const unsigned short* __restrict__ A, const float* __restrict__ Wo,
    float* __restrict__ Out) {
  const int m0 = blockIdx.x * 64, n0 = blockIdx.y * 64;
  const int lane = threadIdx.x;
  const int c = lane & 15, quad = lane >> 4;

  f32x4 zero = {0.f, 0.f, 0.f, 0.f};
  f32x4 acc[4][4];
#pragma unroll
  for (int i = 0; i < 4; ++i)
#pragma unroll
    for (int j = 0; j < 4; ++j) acc[i][j] = zero;

  const unsigned short* ab = A + (size_t)(m0 + c) * DIMN + quad * 8;
  const float* bb = Wo + (size_t)(n0 + c) * DIMN + quad * 8;

  for (int k0 = 0; k0 < DIMN; k0 += 32) {
    s16x8 a[4], b[4];
#pragma unroll
    for (int i = 0; i < 4; ++i) a[i] = *(const s16x8*)(ab + i * 16 * DIMN + k0);
#pragma unroll
    for (int j = 0; j < 4; ++j) {
      const float* pp = bb + j * 16 * DIMN + k0;
      b[j] = cvt8(*(const float4*)pp, *(const float4*)(pp + 4));
    }
#pragma unroll
    for (int i = 0; i < 4; ++i)
#pragma unroll
      for (int j = 0; j < 4; ++j)
        acc[i][j] = __builtin_amdgcn_mfma_f32_16x16x32_bf16(a[i], b[j], acc[i][j], 0, 0, 0);
  }

#pragma unroll
  for (int i = 0; i < 4; ++i)
#pragma unroll
    for (int j = 0; j < 4; ++j)
#pragma unroll
      for (int r = 0; r < 4; ++r)
        Out[(size_t)(m0 + i * 16 + quad * 4 + r) * DIMN + n0 + j * 16 + c] = acc[i][j][r];
}

extern "C" void kernel_launch(void* const* d_in, const int* in_sizes, int n_in,
                              void* d_out, int out_size, void* d_ws, size_t ws_size,
                              hipStream_t stream) {
  const float* X = (const float*)d_in[0];
  const float* Wq = (const float*)d_in[1];
  const float* Wk = (const float*)d_in[2];
  const float* Wv = (const float*)d_in[3];
  const float* Wo = (const float*)d_in[4];
  float* Out = (float*)d_out;

  const size_t M1 = (size_t)1 << 20;
  unsigned short* ws16 = (unsigned short*)d_ws;

  if (ws_size >= (size_t)48 * 1024 * 1024) {
    unsigned short* Xb = ws16;            // 4M elems
    unsigned short* Wb = ws16 + 4 * M1;   // 4 x 1M (Wq,Wk,Wv,Wo contiguous)
    unsigned short* Qb = ws16 + 8 * M1;
    unsigned short* Kb = ws16 + 12 * M1;
    unsigned short* VT = ws16 + 16 * M1;
    unsigned short* AO = ws16 + 20 * M1;
    cvt_all<<<4096, 256, 0, stream>>>(X, Wq, Wk, Wv, Wo, ws16);
    gemm_qkv<<<768, 256, 0, stream>>>(Xb, Wb, Qb, Kb, VT);
    attn6<<<512, 512, 0, stream>>>(Qb, Kb, VT, AO);
    gemm_o<<<512, 256, 0, stream>>>(AO, Wb + 3 * M1, Out);
  } else {
    unsigned short* Qb = ws16;
    unsigned short* Kb = ws16 + 4 * M1;
    unsigned short* VT = ws16 + 8 * M1;
    unsigned short* AO = ws16 + 12 * M1;
    qkv_proj_f<<<dim3(64, 48), 64, 0, stream>>>(X, Wq, Wk, Wv, Qb, Kb, VT);
    attn6<<<512, 512, 0, stream>>>(Qb, Kb, VT, AO);
    o_proj_f<<<dim3(64, 16), 64, 0, stream>>>(AO, Wo, Out);
  }
}